// Round 4
// baseline (1210.084 us; speedup 1.0000x reference)
//
#include <hip/hip_runtime.h>
#include <cstdint>
#include <cstddef>

#define WH 4096
#define CD 256
typedef long long i64;

typedef __attribute__((ext_vector_type(8))) _Float16 f16x8;
typedef __attribute__((ext_vector_type(4))) float f32x4;

#define AS1 __attribute__((address_space(1)))
#define AS3 __attribute__((address_space(3)))

__device__ __forceinline__ unsigned short f2h(float f) {
    _Float16 h = (_Float16)f;
    return __builtin_bit_cast(unsigned short, h);
}
__device__ __forceinline__ float h2f(unsigned short u) {
    return (float)__builtin_bit_cast(_Float16, u);
}
__device__ __forceinline__ void ld16_lds(const void* g, void* l) {
    __builtin_amdgcn_global_load_lds((AS1 void*)g, (AS3 void*)l, 16, 0, 0);
}

// -------- batched transpose f32 -> f16 split; per-z pre-offset pointers
struct TransArgs {
    const float* src[8];
    unsigned short* dhi[8];
    unsigned short* dlo[8];
};
__global__ __launch_bounds__(256) void k_transN(TransArgs ta, int RR, int CC) {
    __shared__ float t[32][33];
    const float* s = ta.src[blockIdx.z];
    unsigned short* dhi = ta.dhi[blockIdx.z];
    unsigned short* dlo = ta.dlo[blockIdx.z];
    const int c0 = blockIdx.x * 32, r0 = blockIdx.y * 32;
    const int tx = threadIdx.x, ty = threadIdx.y;
#pragma unroll
    for (int i = 0; i < 4; ++i)
        t[ty + i * 8][tx] = s[(i64)(r0 + ty + i * 8) * CC + c0 + tx];
    __syncthreads();
#pragma unroll
    for (int i = 0; i < 4; ++i) {
        const i64 idx = (i64)(c0 + ty + i * 8) * RR + r0 + tx;
        const float v = t[tx][ty + i * 8];
        const unsigned short hi = f2h(v);
        dhi[idx] = hi;
        dlo[idx] = f2h(v - h2f(hi));
    }
}

// -------- NT GEMM, f16. SPLIT3=1: (Ah+Al)(Bh+Bl)^T via 3 MFMA products; SPLIT3=0: Ah*Bh^T only.
// MODE 0: f32 store (logits -> Lb) + fused per-block ROW stat partials (max,expsum over 128 cols)
// MODE 1: bias+relu, store transposed f16-split (ax -> axt hi/lo)
// MODE 2: bias+relu, add split residual, f32 store (r -> outf)
template <int MODE, int SPLIT3>
__global__ __launch_bounds__(256) void k_gemm(
    const unsigned short* __restrict__ A, const unsigned short* __restrict__ A2, int lda, i64 sA,
    const unsigned short* __restrict__ B, const unsigned short* __restrict__ B2, int ldb, i64 sB,
    float* __restrict__ Cf, unsigned short* __restrict__ Chi, unsigned short* __restrict__ Clo,
    int ldc, i64 sC, int K,
    const float* __restrict__ bias,
    const unsigned short* __restrict__ addh, const unsigned short* __restrict__ addl,
    float2* __restrict__ rowP) {
    __shared__ __align__(16) short lA[SPLIT3 ? 8192 : 4096];
    __shared__ __align__(16) short lB[SPLIT3 ? 8192 : 4096];
    __shared__ float2 redp[2][128];
    const int z = blockIdx.z;
    A += (i64)z * sA; B += (i64)z * sB;
    if constexpr (SPLIT3) { A2 += (i64)z * sA; B2 += (i64)z * sB; }

    const int tid = threadIdx.x;
    const int w = tid >> 6, l = tid & 63;
    const int wm = w >> 1, wn = w & 1;
    const int bm = blockIdx.y * 128, bn = blockIdx.x * 128;
    const int l15 = l & 15, lq = l >> 4;

    f32x4 acc[4][4] = {};

    for (int kt = 0; kt < K; kt += 32) {
        __syncthreads();
#pragma unroll
        for (int rr = 0; rr < 2; ++rr) {
            const int r = w + rr * 4;          // region 0..7
            const int kb = r >> 1, mh = r & 1;
            const int row = mh * 64 + l;
            const i64 ao = (i64)(bm + row) * lda + kt + kb * 8;
            const i64 bo = (i64)(bn + row) * ldb + kt + kb * 8;
            ld16_lds(A + ao, (char*)lA + r * 1024);
            ld16_lds(B + bo, (char*)lB + r * 1024);
            if constexpr (SPLIT3) {
                ld16_lds(A2 + ao, (char*)lA + 8192 + r * 1024);
                ld16_lds(B2 + bo, (char*)lB + 8192 + r * 1024);
            }
        }
        __syncthreads();
        f16x8 ah[4], bh[4], al[4], bl[4];
#pragma unroll
        for (int i = 0; i < 4; ++i) {
            const int ia = (lq * 128 + wm * 64 + i * 16 + l15) * 8;
            const int ib = (lq * 128 + wn * 64 + i * 16 + l15) * 8;
            ah[i] = *(const f16x8*)(lA + ia);
            bh[i] = *(const f16x8*)(lB + ib);
            if constexpr (SPLIT3) {
                al[i] = *(const f16x8*)(lA + 4096 + ia);
                bl[i] = *(const f16x8*)(lB + 4096 + ib);
            }
        }
#pragma unroll
        for (int i = 0; i < 4; ++i)
#pragma unroll
            for (int j = 0; j < 4; ++j) {
                acc[i][j] = __builtin_amdgcn_mfma_f32_16x16x32_f16(ah[i], bh[j], acc[i][j], 0, 0, 0);
                if constexpr (SPLIT3) {
                    acc[i][j] = __builtin_amdgcn_mfma_f32_16x16x32_f16(ah[i], bl[j], acc[i][j], 0, 0, 0);
                    acc[i][j] = __builtin_amdgcn_mfma_f32_16x16x32_f16(al[i], bh[j], acc[i][j], 0, 0, 0);
                }
            }
    }

#pragma unroll
    for (int i = 0; i < 4; ++i)
#pragma unroll
        for (int j = 0; j < 4; ++j) {
            const int n = bn + wn * 64 + j * 16 + l15;
            const int m0 = bm + wm * 64 + i * 16 + lq * 4;
            float bv = 0.f;
            if constexpr (MODE == 1 || MODE == 2) bv = bias[n];
            if constexpr (MODE == 1) {
                unsigned short hv[4], lv[4];
#pragma unroll
                for (int r = 0; r < 4; ++r) {
                    const float v = fmaxf(acc[i][j][r] + bv, 0.f);
                    hv[r] = f2h(v);
                    lv[r] = f2h(v - h2f(hv[r]));
                }
                const i64 tb = (i64)z * sC + (i64)n * ldc + m0;
                *(ushort4*)(Chi + tb) = make_ushort4(hv[0], hv[1], hv[2], hv[3]);
                *(ushort4*)(Clo + tb) = make_ushort4(lv[0], lv[1], lv[2], lv[3]);
            } else {
#pragma unroll
                for (int r = 0; r < 4; ++r) {
                    float v = acc[i][j][r];
                    const i64 idx = (i64)z * sC + (i64)(m0 + r) * ldc + n;
                    if constexpr (MODE == 0) {
                        Cf[idx] = v;
                    } else {  // MODE 2
                        v = fmaxf(v + bv, 0.f);
                        v += h2f(addh[idx]) + h2f(addl[idx]);
                        Cf[idx] = v;
                    }
                }
            }
        }

    if constexpr (MODE == 0) {
        // ---- fused row partials: (max, expsum) over this block's 128 cols, per row.
        float rm[16], rs[16];
#pragma unroll
        for (int i = 0; i < 4; ++i)
#pragma unroll
            for (int r = 0; r < 4; ++r) {
                float m = fmaxf(fmaxf(acc[i][0][r], acc[i][1][r]), fmaxf(acc[i][2][r], acc[i][3][r]));
                m = fmaxf(m, __shfl_xor(m, 1));
                m = fmaxf(m, __shfl_xor(m, 2));
                m = fmaxf(m, __shfl_xor(m, 4));
                m = fmaxf(m, __shfl_xor(m, 8));
                rm[i * 4 + r] = m;
                float s = __expf(acc[i][0][r] - m) + __expf(acc[i][1][r] - m)
                        + __expf(acc[i][2][r] - m) + __expf(acc[i][3][r] - m);
                s += __shfl_xor(s, 1); s += __shfl_xor(s, 2);
                s += __shfl_xor(s, 4); s += __shfl_xor(s, 8);
                rs[i * 4 + r] = s;
            }
        __syncthreads();
        if (l15 == 0) {
#pragma unroll
            for (int i = 0; i < 4; ++i)
#pragma unroll
                for (int r = 0; r < 4; ++r)
                    redp[wn][wm * 64 + i * 16 + lq * 4 + r] = make_float2(rm[i * 4 + r], rs[i * 4 + r]);
        }
        __syncthreads();
        if (tid < 128) {
            const float2 a = redp[0][tid], b = redp[1][tid];
            const float m = fmaxf(a.x, b.x);
            const float s = a.y * __expf(a.x - m) + b.y * __expf(b.x - m);
            rowP[(i64)blockIdx.x * WH + bm + tid] = make_float2(m, s);
        }
    }
}

// -------- fused: merge row partials -> o (own 64 rows, in LDS); col partials = plain exp-sum.
// grid (16, 64). Block x==0 publishes o for its row range.
__global__ __launch_bounds__(256) void k_colpart(const float* __restrict__ L,
                                                 const float2* __restrict__ rowP,
                                                 float* __restrict__ o,
                                                 float* __restrict__ part) {
    __shared__ float os[64];
    const int t = threadIdx.x;
    const int r0 = blockIdx.y * 64;
    if (t < 64) {
        float M = -3.4e38f, S = 0.f;
        for (int x = 0; x < 32; ++x) {
            const float2 p = rowP[(i64)x * WH + r0 + t];
            const float nm = fmaxf(M, p.x);
            S = S * __expf(M - nm) + p.y * __expf(p.x - nm);
            M = nm;
        }
        const float ov = M + __logf(S);
        os[t] = ov;
        if (blockIdx.x == 0) o[r0 + t] = ov;
    }
    __syncthreads();
    const int j = blockIdx.x * 256 + t;
    float ps = 0.f;
    for (int r = 0; r < 64; ++r)
        ps += __expf(L[(i64)(r0 + r) * WH + j] - os[r]);
    part[(i64)blockIdx.y * WH + j] = ps;
}

// -------- fused attention: P = [exp(L - o_i) * colS_j] @ axt^T, direct f32 atomic accumulate.
// colS computed in-prologue from part (replaces k_colreduce dispatch; bit-identical summation).
// FULL=1: split A and B (3 MFMA); FULL=0: hi-only.
// grid (2, 32, 8): z = k-chunk of 512.
template <int FULL>
__global__ __launch_bounds__(256) void k_attn(
    const float* __restrict__ L, const float* __restrict__ o,
    const float* __restrict__ part,
    const unsigned short* __restrict__ Bh, const unsigned short* __restrict__ Bl,
    float* __restrict__ Of) {
    __shared__ __align__(16) float lL[4096];   // 16 KB: 128 rows x 32 k (crossed chunks)
    __shared__ __align__(16) short lBh[4096];  // 8 KB
    __shared__ __align__(16) short lBl[FULL ? 4096 : 64];
    __shared__ float lS[512];
    const int tid = threadIdx.x;
    const int w = tid >> 6, l = tid & 63;
    const int wm = w >> 1, wn = w & 1;
    const int bm = blockIdx.y * 128, bn = blockIdx.x * 128;
    const int l15 = l & 15, lq = l >> 4;
    const i64 koff = (i64)blockIdx.z * 512;

    // colS for this k-chunk, from part (same summation order as old k_colreduce)
    {
        float C0 = 0.f, C1 = 0.f;
#pragma unroll 4
        for (int p = 0; p < 64; ++p) {
            C0 += part[(i64)p * WH + koff + tid];
            C1 += part[(i64)p * WH + koff + 256 + tid];
        }
        lS[tid] = 1.f / fmaxf(C0, 1e-12f);
        lS[tid + 256] = 1.f / fmaxf(C1, 1e-12f);
    }
    float o4[4];
#pragma unroll
    for (int i = 0; i < 4; ++i) o4[i] = o[bm + wm * 64 + i * 16 + l15];

    f32x4 acc[4][4] = {};
    for (int kt = 0; kt < 512; kt += 32) {
        __syncthreads();
#pragma unroll
        for (int rr = 0; rr < 4; ++rr) {
            const int r = w + rr * 4;          // region 0..15 (1 KB each)
            const int kb2 = r >> 1, mh = r & 1;
            ld16_lds(L + (i64)(bm + mh * 64 + l) * WH + koff + kt + kb2 * 4,
                     (char*)lL + r * 1024);
        }
#pragma unroll
        for (int rr = 0; rr < 2; ++rr) {
            const int r = w + rr * 4;          // region 0..7
            const int kb = r >> 1, mh = r & 1;
            const i64 bo = (i64)(bn + mh * 64 + l) * WH + koff + kt + kb * 8;
            ld16_lds(Bh + bo, (char*)lBh + r * 1024);
            if constexpr (FULL) ld16_lds(Bl + bo, (char*)lBl + r * 1024);
        }
        __syncthreads();
        float sv[8];
        *(float4*)(sv)     = *(const float4*)(lS + kt + lq * 8);
        *(float4*)(sv + 4) = *(const float4*)(lS + kt + lq * 8 + 4);
        f16x8 bh[4], bl[4];
#pragma unroll
        for (int j = 0; j < 4; ++j) {
            const int ib = (lq * 128 + wn * 64 + j * 16 + l15) * 8;
            bh[j] = *(const f16x8*)(lBh + ib);
            if constexpr (FULL) bl[j] = *(const f16x8*)(lBl + ib);
        }
#pragma unroll
        for (int i = 0; i < 4; ++i) {
            const int mrow = wm * 64 + i * 16 + l15;
            const float* lp = lL + lq * 1024 + mrow * 4;
            float xv[8];
            *(float4*)(xv)     = *(const float4*)(lp);
            *(float4*)(xv + 4) = *(const float4*)(lp + 512);
            const float oi = o4[i];
            f16x8 ah, al;
#pragma unroll
            for (int e = 0; e < 8; ++e) {
                const float a = __expf(xv[e] - oi) * sv[e];
                const _Float16 hh = (_Float16)a;
                ah[e] = hh;
                if constexpr (FULL) al[e] = (_Float16)(a - (float)hh);
            }
#pragma unroll
            for (int j = 0; j < 4; ++j) {
                acc[i][j] = __builtin_amdgcn_mfma_f32_16x16x32_f16(ah, bh[j], acc[i][j], 0, 0, 0);
                if constexpr (FULL) {
                    acc[i][j] = __builtin_amdgcn_mfma_f32_16x16x32_f16(ah, bl[j], acc[i][j], 0, 0, 0);
                    acc[i][j] = __builtin_amdgcn_mfma_f32_16x16x32_f16(al, bh[j], acc[i][j], 0, 0, 0);
                }
            }
        }
    }
    // direct f32 accumulate into outf (replaces Pw f16 partials + k_red)
#pragma unroll
    for (int i = 0; i < 4; ++i)
#pragma unroll
        for (int j = 0; j < 4; ++j) {
            const int n = bn + wn * 64 + j * 16 + l15;
            const int m0 = bm + wm * 64 + i * 16 + lq * 4;
#pragma unroll
            for (int r = 0; r < 4; ++r)
                unsafeAtomicAdd(Of + (i64)(m0 + r) * CD + n, acc[i][j][r]);
        }
}

// -------- emit f16 split of a f32 buffer (stage A: gen -> ghi/glo)
__global__ __launch_bounds__(256) void k_split(const float* __restrict__ p,
                                               unsigned short* __restrict__ hi,
                                               unsigned short* __restrict__ lo) {
    const i64 i = ((i64)blockIdx.x * 256 + threadIdx.x) * 4;
    const float4 a = *(const float4*)(p + i);
    ushort4 h, l2;
    h.x = f2h(a.x); l2.x = f2h(a.x - h2f(h.x));
    h.y = f2h(a.y); l2.y = f2h(a.y - h2f(h.y));
    h.z = f2h(a.z); l2.z = f2h(a.z - h2f(h.z));
    h.w = f2h(a.w); l2.w = f2h(a.w - h2f(h.w));
    *(ushort4*)(hi + i) = h;
    *(ushort4*)(lo + i) = l2;
}

extern "C" void kernel_launch(void* const* d_in, const int* in_sizes, int n_in,
                              void* d_out, int out_size, void* d_ws, size_t ws_size,
                              hipStream_t stream) {
    (void)in_sizes; (void)n_in; (void)out_size; (void)ws_size;
    const float* skt = (const float*)d_in[0];
    const float* ref = (const float*)d_in[1];
    const float* Wa3 = (const float*)d_in[2];
    const float* ba3 = (const float*)d_in[3];
    const float* Wu3 = (const float*)d_in[4];
    const float* bu3 = (const float*)d_in[5];
    const float* Wa4 = (const float*)d_in[6];
    const float* ba4 = (const float*)d_in[7];
    const float* Wu4 = (const float*)d_in[8];
    const float* bu4 = (const float*)d_in[9];
    float* out = (float*)d_out;

    const i64 WHC = (i64)WH * CD;   // 1,048,576
    const i64 GM  = (i64)WH * WH;   // 16,777,216
    const i64 CC  = (i64)CD * CD;

    // workspace carve — total ~135 MB (proven-safe: 204.5 MB ran previously)
    auto al = [](size_t x) { return (x + 255) & ~(size_t)255; };
    char* p = (char*)d_ws; size_t off = 0;
    auto carve = [&](size_t bytes) { void* r = p + off; off += al(bytes); return r; };
    float* Lb             = (float*)carve((size_t)GM * 4);               // 67.1 MB
    unsigned short* skthi = (unsigned short*)carve((size_t)4 * WHC * 2);
    unsigned short* sktlo = (unsigned short*)carve((size_t)4 * WHC * 2);
    unsigned short* refhi = (unsigned short*)carve((size_t)4 * WHC * 2);
    unsigned short* reflo = (unsigned short*)carve((size_t)4 * WHC * 2);
    unsigned short* ghi   = (unsigned short*)carve((size_t)4 * WHC * 2);
    unsigned short* glo   = (unsigned short*)carve((size_t)4 * WHC * 2); // 6x8.39 MB
    unsigned short* axthi = (unsigned short*)carve((size_t)4 * WHC * 2);
    unsigned short* axtlo = (unsigned short*)carve((size_t)4 * WHC * 2); // 16.8 MB
    float* ob             = (float*)carve((size_t)WH * 4);
    float* partb          = (float*)carve((size_t)64 * WH * 4);          // 1.05 MB
    float2* rowPb         = (float2*)carve((size_t)32 * WH * 8);         // 1.05 MB
    unsigned short* Wthi  = (unsigned short*)carve((size_t)4 * CC * 2);
    unsigned short* Wtlo  = (unsigned short*)carve((size_t)4 * CC * 2);

    dim3 thr(256), ttr(32, 8);
    // batched transposes: one dispatch for skt+ref (8 z), one for the 4 weights
    {
        TransArgs ta{};
        for (int b = 0; b < 4; ++b) {
            ta.src[b] = skt + (i64)b * WHC;     ta.src[b + 4] = ref + (i64)b * WHC;
            ta.dhi[b] = skthi + (i64)b * WHC;   ta.dhi[b + 4] = refhi + (i64)b * WHC;
            ta.dlo[b] = sktlo + (i64)b * WHC;   ta.dlo[b + 4] = reflo + (i64)b * WHC;
        }
        k_transN<<<dim3(WH / 32, CD / 32, 8), ttr, 0, stream>>>(ta, CD, WH);
        TransArgs tw{};
        const float* ws[4] = { Wa3, Wu3, Wa4, Wu4 };
        for (int i = 0; i < 4; ++i) {
            tw.src[i] = ws[i];
            tw.dhi[i] = Wthi + (i64)i * CC;
            tw.dlo[i] = Wtlo + (i64)i * CC;
        }
        k_transN<<<dim3(CD / 32, CD / 32, 4), ttr, 0, stream>>>(tw, CD, CD);
    }

    // FULL3 = 1: stage A (split attn path, emits gen split); 0: stage B (hi-only attn)
    auto stage = [&](const unsigned short* shi, const unsigned short* slo,
                     const unsigned short* mhi, const unsigned short* mlo,
                     int widx, const float* ba, const float* bu, float* outf,
                     unsigned short* ohi, unsigned short* olo, int FULL3) {
        // ax = relu(msg @ Wa + ba), stored transposed as f16 split (all 4 batches)
        if (FULL3)
            k_gemm<1, 1><<<dim3(CD / 128, WH / 128, 4), thr, 0, stream>>>(
                mhi, mlo, CD, WHC, Wthi + (i64)widx * CC, Wtlo + (i64)widx * CC, CD, 0,
                nullptr, axthi, axtlo, WH, WHC, CD, ba, nullptr, nullptr, nullptr);
        else
            k_gemm<1, 0><<<dim3(CD / 128, WH / 128, 4), thr, 0, stream>>>(
                mhi, nullptr, CD, WHC, Wthi + (i64)widx * CC, nullptr, CD, 0,
                nullptr, axthi, axtlo, WH, WHC, CD, ba, nullptr, nullptr, nullptr);
        // r = relu(src @ Wu + bu) + src  -> outf (all 4 batches)
        if (FULL3)
            k_gemm<2, 1><<<dim3(CD / 128, WH / 128, 4), thr, 0, stream>>>(
                shi, slo, CD, WHC, Wthi + (i64)(widx + 1) * CC, Wtlo + (i64)(widx + 1) * CC, CD, 0,
                outf, nullptr, nullptr, CD, WHC, CD, bu, shi, slo, nullptr);
        else
            k_gemm<2, 0><<<dim3(CD / 128, WH / 128, 4), thr, 0, stream>>>(
                shi, nullptr, CD, WHC, Wthi + (i64)(widx + 1) * CC, nullptr, CD, 0,
                outf, nullptr, nullptr, CD, WHC, CD, bu, shi, slo, nullptr);
        for (int b = 0; b < 4; ++b) {
            // logits -> Lb (f32) + fused row-stat partials — ALWAYS split (pre-softmax)
            k_gemm<0, 1><<<dim3(WH / 128, WH / 128, 1), thr, 0, stream>>>(
                shi + (i64)b * WHC, slo + (i64)b * WHC, CD, 0,
                mhi + (i64)b * WHC, mlo + (i64)b * WHC, CD, 0,
                Lb, nullptr, nullptr, WH, 0, CD, nullptr, nullptr, nullptr, rowPb);
            // fused o-finalize + col partials (plain f32 exp-sums)
            k_colpart<<<dim3(WH / 256, WH / 64, 1), thr, 0, stream>>>(Lb, rowPb, ob, partb);
            // attention: colS in-prologue from part; direct f32 atomic accumulate into outf
            if (FULL3)
                k_attn<1><<<dim3(CD / 128, WH / 128, 8), thr, 0, stream>>>(
                    Lb, ob, partb, axthi + (i64)b * WHC, axtlo + (i64)b * WHC,
                    outf + (i64)b * WHC);
            else
                k_attn<0><<<dim3(CD / 128, WH / 128, 8), thr, 0, stream>>>(
                    Lb, ob, partb, axthi + (i64)b * WHC, nullptr,
                    outf + (i64)b * WHC);
            // stage A: emit f16 split of gen for stage B
            if (ohi)
                k_split<<<dim3((unsigned)(WHC / 1024)), thr, 0, stream>>>(
                    outf + (i64)b * WHC, ohi + (i64)b * WHC, olo + (i64)b * WHC);
        }
    };

    // stage A: src = skt, msg = ref -> gen (accumulated in d_out, split to ghi/glo)
    stage(skthi, sktlo, refhi, reflo, 0, ba3, bu3, out, ghi, glo, 1);
    // stage B: src = msg = gen -> final output (overwrites d_out)
    stage(ghi, glo, ghi, glo, 2, ba4, bu4, out, nullptr, nullptr, 0);
}

// Round 6
// 1118.255 us; speedup vs baseline: 1.0821x; 1.0821x over previous
//
#include <hip/hip_runtime.h>
#include <cstdint>
#include <cstddef>

#define WH 4096
#define CD 256
typedef long long i64;

typedef __attribute__((ext_vector_type(8))) _Float16 f16x8;
typedef __attribute__((ext_vector_type(4))) float f32x4;

#define AS1 __attribute__((address_space(1)))
#define AS3 __attribute__((address_space(3)))

__device__ __forceinline__ unsigned short f2h(float f) {
    _Float16 h = (_Float16)f;
    return __builtin_bit_cast(unsigned short, h);
}
__device__ __forceinline__ float h2f(unsigned short u) {
    return (float)__builtin_bit_cast(_Float16, u);
}
__device__ __forceinline__ void ld16_lds(const void* g, void* l) {
    __builtin_amdgcn_global_load_lds((AS1 void*)g, (AS3 void*)l, 16, 0, 0);
}

// -------- batched transpose f32 -> f16 split; per-z pre-offset pointers
struct TransArgs {
    const float* src[8];
    unsigned short* dhi[8];
    unsigned short* dlo[8];
};
__global__ __launch_bounds__(256) void k_transN(TransArgs ta, int RR, int CC) {
    __shared__ float t[32][33];
    const float* s = ta.src[blockIdx.z];
    unsigned short* dhi = ta.dhi[blockIdx.z];
    unsigned short* dlo = ta.dlo[blockIdx.z];
    const int c0 = blockIdx.x * 32, r0 = blockIdx.y * 32;
    const int tx = threadIdx.x, ty = threadIdx.y;
#pragma unroll
    for (int i = 0; i < 4; ++i)
        t[ty + i * 8][tx] = s[(i64)(r0 + ty + i * 8) * CC + c0 + tx];
    __syncthreads();
#pragma unroll
    for (int i = 0; i < 4; ++i) {
        const i64 idx = (i64)(c0 + ty + i * 8) * RR + r0 + tx;
        const float v = t[tx][ty + i * 8];
        const unsigned short hi = f2h(v);
        dhi[idx] = hi;
        dlo[idx] = f2h(v - h2f(hi));
    }
}

// -------- NT GEMM, f16. SPLIT3=1: 3 MFMA products; SPLIT3=0: hi only.
// MODE 1: bias+relu, store transposed f16-split (ax -> axt hi/lo)
// MODE 2: bias+relu, add split residual, f32 store (r -> outf)
template <int MODE, int SPLIT3>
__global__ __launch_bounds__(256) void k_gemm(
    const unsigned short* __restrict__ A, const unsigned short* __restrict__ A2, int lda, i64 sA,
    const unsigned short* __restrict__ B, const unsigned short* __restrict__ B2, int ldb, i64 sB,
    float* __restrict__ Cf, unsigned short* __restrict__ Chi, unsigned short* __restrict__ Clo,
    int ldc, i64 sC, int K,
    const float* __restrict__ bias,
    const unsigned short* __restrict__ addh, const unsigned short* __restrict__ addl) {
    __shared__ __align__(16) short lA[SPLIT3 ? 8192 : 4096];
    __shared__ __align__(16) short lB[SPLIT3 ? 8192 : 4096];
    const int z = blockIdx.z;
    A += (i64)z * sA; B += (i64)z * sB;
    if constexpr (SPLIT3) { A2 += (i64)z * sA; B2 += (i64)z * sB; }

    const int tid = threadIdx.x;
    const int w = tid >> 6, l = tid & 63;
    const int wm = w >> 1, wn = w & 1;
    const int bm = blockIdx.y * 128, bn = blockIdx.x * 128;
    const int l15 = l & 15, lq = l >> 4;

    f32x4 acc[4][4] = {};

    for (int kt = 0; kt < K; kt += 32) {
        __syncthreads();
#pragma unroll
        for (int rr = 0; rr < 2; ++rr) {
            const int r = w + rr * 4;          // region 0..7
            const int kb = r >> 1, mh = r & 1;
            const int row = mh * 64 + l;
            const i64 ao = (i64)(bm + row) * lda + kt + kb * 8;
            const i64 bo = (i64)(bn + row) * ldb + kt + kb * 8;
            ld16_lds(A + ao, (char*)lA + r * 1024);
            ld16_lds(B + bo, (char*)lB + r * 1024);
            if constexpr (SPLIT3) {
                ld16_lds(A2 + ao, (char*)lA + 8192 + r * 1024);
                ld16_lds(B2 + bo, (char*)lB + 8192 + r * 1024);
            }
        }
        __syncthreads();
        f16x8 ah[4], bh[4], al[4], bl[4];
#pragma unroll
        for (int i = 0; i < 4; ++i) {
            const int ia = (lq * 128 + wm * 64 + i * 16 + l15) * 8;
            const int ib = (lq * 128 + wn * 64 + i * 16 + l15) * 8;
            ah[i] = *(const f16x8*)(lA + ia);
            bh[i] = *(const f16x8*)(lB + ib);
            if constexpr (SPLIT3) {
                al[i] = *(const f16x8*)(lA + 4096 + ia);
                bl[i] = *(const f16x8*)(lB + 4096 + ib);
            }
        }
#pragma unroll
        for (int i = 0; i < 4; ++i)
#pragma unroll
            for (int j = 0; j < 4; ++j) {
                acc[i][j] = __builtin_amdgcn_mfma_f32_16x16x32_f16(ah[i], bh[j], acc[i][j], 0, 0, 0);
                if constexpr (SPLIT3) {
                    acc[i][j] = __builtin_amdgcn_mfma_f32_16x16x32_f16(ah[i], bl[j], acc[i][j], 0, 0, 0);
                    acc[i][j] = __builtin_amdgcn_mfma_f32_16x16x32_f16(al[i], bh[j], acc[i][j], 0, 0, 0);
                }
            }
    }

#pragma unroll
    for (int i = 0; i < 4; ++i)
#pragma unroll
        for (int j = 0; j < 4; ++j) {
            const int n = bn + wn * 64 + j * 16 + l15;
            const int m0 = bm + wm * 64 + i * 16 + lq * 4;
            const float bv = bias[n];
            if constexpr (MODE == 1) {
                unsigned short hv[4], lv[4];
#pragma unroll
                for (int r = 0; r < 4; ++r) {
                    const float v = fmaxf(acc[i][j][r] + bv, 0.f);
                    hv[r] = f2h(v);
                    lv[r] = f2h(v - h2f(hv[r]));
                }
                const i64 tb = (i64)z * sC + (i64)n * ldc + m0;
                *(ushort4*)(Chi + tb) = make_ushort4(hv[0], hv[1], hv[2], hv[3]);
                *(ushort4*)(Clo + tb) = make_ushort4(lv[0], lv[1], lv[2], lv[3]);
            } else {  // MODE 2
#pragma unroll
                for (int r = 0; r < 4; ++r) {
                    const i64 idx = (i64)z * sC + (i64)(m0 + r) * ldc + n;
                    float v = fmaxf(acc[i][j][r] + bv, 0.f);
                    v += h2f(addh[idx]) + h2f(addl[idx]);
                    Cf[idx] = v;
                }
            }
        }
}

// -------- logits GEMM (split-3) -> stores gs = 256*exp((L - m_half)/2) as f16, plus rowP.
// Scaled sqrt-domain: g = gs^2 * exp(m_half - o) / 65536 is recoverable with ~1e-3 relative
// error down to g ~ 5.7e-14 (below the reference's 1e-12 colsum clip -> no resurrection bug).
// rowP layout: [64 half-tiles][WH rows] of (m_half, expsum_half); half = blockIdx.x*2 + wn.
__global__ __launch_bounds__(256) void k_logits(
    const unsigned short* __restrict__ A, const unsigned short* __restrict__ A2,
    const unsigned short* __restrict__ B, const unsigned short* __restrict__ B2,
    unsigned short* __restrict__ G, float2* __restrict__ rowP) {
    __shared__ __align__(16) short lA[8192];
    __shared__ __align__(16) short lB[8192];
    const int tid = threadIdx.x;
    const int w = tid >> 6, l = tid & 63;
    const int wm = w >> 1, wn = w & 1;
    const int bm = blockIdx.y * 128, bn = blockIdx.x * 128;
    const int l15 = l & 15, lq = l >> 4;

    f32x4 acc[4][4] = {};

    for (int kt = 0; kt < CD; kt += 32) {
        __syncthreads();
#pragma unroll
        for (int rr = 0; rr < 2; ++rr) {
            const int r = w + rr * 4;          // region 0..7
            const int kb = r >> 1, mh = r & 1;
            const int row = mh * 64 + l;
            const i64 ao = (i64)(bm + row) * CD + kt + kb * 8;
            const i64 bo = (i64)(bn + row) * CD + kt + kb * 8;
            ld16_lds(A + ao, (char*)lA + r * 1024);
            ld16_lds(B + bo, (char*)lB + r * 1024);
            ld16_lds(A2 + ao, (char*)lA + 8192 + r * 1024);
            ld16_lds(B2 + bo, (char*)lB + 8192 + r * 1024);
        }
        __syncthreads();
        f16x8 ah[4], bh[4], al[4], bl[4];
#pragma unroll
        for (int i = 0; i < 4; ++i) {
            const int ia = (lq * 128 + wm * 64 + i * 16 + l15) * 8;
            const int ib = (lq * 128 + wn * 64 + i * 16 + l15) * 8;
            ah[i] = *(const f16x8*)(lA + ia);
            bh[i] = *(const f16x8*)(lB + ib);
            al[i] = *(const f16x8*)(lA + 4096 + ia);
            bl[i] = *(const f16x8*)(lB + 4096 + ib);
        }
#pragma unroll
        for (int i = 0; i < 4; ++i)
#pragma unroll
            for (int j = 0; j < 4; ++j) {
                acc[i][j] = __builtin_amdgcn_mfma_f32_16x16x32_f16(ah[i], bh[j], acc[i][j], 0, 0, 0);
                acc[i][j] = __builtin_amdgcn_mfma_f32_16x16x32_f16(ah[i], bl[j], acc[i][j], 0, 0, 0);
                acc[i][j] = __builtin_amdgcn_mfma_f32_16x16x32_f16(al[i], bh[j], acc[i][j], 0, 0, 0);
            }
    }

    // epilogue: per (row, wn-half): m over 64 cols, gs f16 store, exact f32 expsum, rowP store
#pragma unroll
    for (int i = 0; i < 4; ++i)
#pragma unroll
        for (int r = 0; r < 4; ++r) {
            const int grow = bm + wm * 64 + i * 16 + lq * 4 + r;
            float m = fmaxf(fmaxf(acc[i][0][r], acc[i][1][r]), fmaxf(acc[i][2][r], acc[i][3][r]));
            m = fmaxf(m, __shfl_xor(m, 1));
            m = fmaxf(m, __shfl_xor(m, 2));
            m = fmaxf(m, __shfl_xor(m, 4));
            m = fmaxf(m, __shfl_xor(m, 8));
            float s = 0.f;
#pragma unroll
            for (int j = 0; j < 4; ++j) {
                const float es = __expf((acc[i][j][r] - m) * 0.5f);
                s += es * es;   // exact exp(L-m) rowsum in f32
                G[(i64)grow * WH + bn + wn * 64 + j * 16 + l15] = f2h(es * 256.f);
            }
            s += __shfl_xor(s, 1); s += __shfl_xor(s, 2);
            s += __shfl_xor(s, 4); s += __shfl_xor(s, 8);
            if (l15 == 0)
                rowP[(i64)(blockIdx.x * 2 + wn) * WH + grow] = make_float2(m, s);
        }
}

// -------- fused: merge rowP (64 halves) -> o; col partials = sum gs^2 * factor.
// factor = exp(m_half - o)/65536 undoes the sqrt-domain scaling. grid (16, 64).
__global__ __launch_bounds__(256) void k_colpart(const unsigned short* __restrict__ G,
                                                 const float2* __restrict__ rowP,
                                                 float* __restrict__ o,
                                                 float* __restrict__ part) {
    __shared__ float os[64];
    __shared__ float fl[4][64];
    const int t = threadIdx.x;
    const int r0 = blockIdx.y * 64;
    if (t < 64) {
        float M = -3.4e38f, S = 0.f;
        for (int x = 0; x < 64; ++x) {
            const float2 p = rowP[(i64)x * WH + r0 + t];
            const float nm = fmaxf(M, p.x);
            S = S * __expf(M - nm) + p.y * __expf(p.x - nm);
            M = nm;
        }
        const float ov = M + __logf(S);
        os[t] = ov;
        if (blockIdx.x == 0) o[r0 + t] = ov;
    }
    __syncthreads();
    {   // 256 factors: (r, jt) for this block's 4 column half-tiles
        const int jt = t & 3, r = t >> 2;
        fl[jt][r] = __expf(rowP[(i64)(blockIdx.x * 4 + jt) * WH + r0 + r].x - os[r])
                  * (1.f / 65536.f);
    }
    __syncthreads();
    const int j = blockIdx.x * 256 + t;
    const int jt = t >> 6;
    float ps = 0.f;
#pragma unroll 4
    for (int r = 0; r < 64; ++r) {
        const float gv = h2f(G[(i64)(r0 + r) * WH + j]);
        ps += gv * gv * fl[jt][r];
    }
    part[(i64)blockIdx.y * WH + j] = ps;
}

// -------- fused attention: P = [gs^2 * exp(m_half-o)/65536 * colS_j] @ axt^T, f32 partials.
// colS computed in-prologue from part. No exp in the inner loop (3 muls per element).
// FULL=1: split A and B (3 MFMA); FULL=0: hi-only. grid (2, 32, 8): z = k-chunk of 512.
template <int FULL>
__global__ __launch_bounds__(256) void k_attn(
    const unsigned short* __restrict__ G, const float* __restrict__ o,
    const float2* __restrict__ rowP, const float* __restrict__ part,
    const unsigned short* __restrict__ Bh, const unsigned short* __restrict__ Bl,
    float* __restrict__ Pw) {
    __shared__ __align__(16) short lL[4096];   // 8 KB: gs 128 rows x 32 k
    __shared__ __align__(16) short lBh[4096];  // 8 KB
    __shared__ __align__(16) short lBl[FULL ? 4096 : 8];
    __shared__ float lS[512];
    const int tid = threadIdx.x;
    const int w = tid >> 6, l = tid & 63;
    const int wm = w >> 1, wn = w & 1;
    const int bm = blockIdx.y * 128, bn = blockIdx.x * 128;
    const int l15 = l & 15, lq = l >> 4;
    const i64 koff = (i64)blockIdx.z * 512;

    // colS for this k-chunk from part (same summation order as the old k_colreduce)
    {
        float C0 = 0.f, C1 = 0.f;
#pragma unroll 4
        for (int p = 0; p < 64; ++p) {
            C0 += part[(i64)p * WH + koff + tid];
            C1 += part[(i64)p * WH + koff + 256 + tid];
        }
        lS[tid] = 1.f / fmaxf(C0, 1e-12f);
        lS[tid + 256] = 1.f / fmaxf(C1, 1e-12f);
    }
    float o4[4];
#pragma unroll
    for (int i = 0; i < 4; ++i) o4[i] = o[bm + wm * 64 + i * 16 + l15];

    float fi[4];
    f32x4 acc[4][4] = {};
    for (int kt = 0; kt < 512; kt += 32) {
        __syncthreads();
#pragma unroll
        for (int rr = 0; rr < 2; ++rr) {
            const int r = w + rr * 4;          // region 0..7 (1 KB each) — gs staging
            const int kb = r >> 1, mh = r & 1;
            ld16_lds(G + (i64)(bm + mh * 64 + l) * WH + koff + kt + kb * 8,
                     (char*)lL + r * 1024);
        }
#pragma unroll
        for (int rr = 0; rr < 2; ++rr) {
            const int r = w + rr * 4;          // region 0..7
            const int kb = r >> 1, mh = r & 1;
            const i64 bo = (i64)(bn + mh * 64 + l) * WH + koff + kt + kb * 8;
            ld16_lds(Bh + bo, (char*)lBh + r * 1024);
            if constexpr (FULL) ld16_lds(Bl + bo, (char*)lBl + r * 1024);
        }
        // per-(row, 64-k-half) factor exp(m_half - o)/65536: refresh every other K-step
        if ((kt & 32) == 0) {
            const i64 half = (koff + kt) >> 6;
#pragma unroll
            for (int i = 0; i < 4; ++i)
                fi[i] = __expf(rowP[half * WH + bm + wm * 64 + i * 16 + l15].x - o4[i])
                      * (1.f / 65536.f);
        }
        __syncthreads();
        float sv[8];
        *(float4*)(sv)     = *(const float4*)(lS + kt + lq * 8);
        *(float4*)(sv + 4) = *(const float4*)(lS + kt + lq * 8 + 4);
        f16x8 bh[4], bl[4];
#pragma unroll
        for (int j = 0; j < 4; ++j) {
            const int ib = (lq * 128 + wn * 64 + j * 16 + l15) * 8;
            bh[j] = *(const f16x8*)(lBh + ib);
            if constexpr (FULL) bl[j] = *(const f16x8*)(lBl + ib);
        }
#pragma unroll
        for (int i = 0; i < 4; ++i) {
            const f16x8 graw = *(const f16x8*)(lL + (lq * 128 + wm * 64 + i * 16 + l15) * 8);
            const float fi_ = fi[i];
            f16x8 ah, al;
#pragma unroll
            for (int e = 0; e < 8; ++e) {
                const float gv = (float)graw[e];
                const float a = gv * gv * fi_ * sv[e];
                const _Float16 hh = (_Float16)a;
                ah[e] = hh;
                if constexpr (FULL) al[e] = (_Float16)(a - (float)hh);
            }
#pragma unroll
            for (int j = 0; j < 4; ++j) {
                acc[i][j] = __builtin_amdgcn_mfma_f32_16x16x32_f16(ah, bh[j], acc[i][j], 0, 0, 0);
                if constexpr (FULL) {
                    acc[i][j] = __builtin_amdgcn_mfma_f32_16x16x32_f16(ah, bl[j], acc[i][j], 0, 0, 0);
                    acc[i][j] = __builtin_amdgcn_mfma_f32_16x16x32_f16(al, bh[j], acc[i][j], 0, 0, 0);
                }
            }
        }
    }
    float* P = Pw + (i64)blockIdx.z * ((i64)WH * CD);
#pragma unroll
    for (int i = 0; i < 4; ++i)
#pragma unroll
        for (int j = 0; j < 4; ++j) {
            const int n = bn + wn * 64 + j * 16 + l15;
            const int m0 = bm + wm * 64 + i * 16 + lq * 4;
#pragma unroll
            for (int r = 0; r < 4; ++r)
                P[(i64)(m0 + r) * CD + n] = acc[i][j][r];
        }
}

// -------- reduce 8 f32 split-K partials into outf (holds r); optionally emit f16 split of result
template <int SPLIT>
__global__ __launch_bounds__(256) void k_red(const float* __restrict__ Pw,
                                             float* __restrict__ outp,
                                             unsigned short* __restrict__ hi,
                                             unsigned short* __restrict__ lo) {
    const i64 i = ((i64)blockIdx.x * 256 + threadIdx.x) * 4;
    float4 a = *(const float4*)(outp + i);
#pragma unroll
    for (int z = 0; z < 8; ++z) {
        const float4 p = *(const float4*)(Pw + (i64)z * ((i64)WH * CD) + i);
        a.x += p.x; a.y += p.y; a.z += p.z; a.w += p.w;
    }
    *(float4*)(outp + i) = a;
    if constexpr (SPLIT) {
        ushort4 h, l2;
        h.x = f2h(a.x); l2.x = f2h(a.x - h2f(h.x));
        h.y = f2h(a.y); l2.y = f2h(a.y - h2f(h.y));
        h.z = f2h(a.z); l2.z = f2h(a.z - h2f(h.z));
        h.w = f2h(a.w); l2.w = f2h(a.w - h2f(h.w));
        *(ushort4*)(hi + i) = h;
        *(ushort4*)(lo + i) = l2;
    }
}

extern "C" void kernel_launch(void* const* d_in, const int* in_sizes, int n_in,
                              void* d_out, int out_size, void* d_ws, size_t ws_size,
                              hipStream_t stream) {
    (void)in_sizes; (void)n_in; (void)out_size; (void)ws_size;
    const float* skt = (const float*)d_in[0];
    const float* ref = (const float*)d_in[1];
    const float* Wa3 = (const float*)d_in[2];
    const float* ba3 = (const float*)d_in[3];
    const float* Wu3 = (const float*)d_in[4];
    const float* bu3 = (const float*)d_in[5];
    const float* Wa4 = (const float*)d_in[6];
    const float* ba4 = (const float*)d_in[7];
    const float* Wu4 = (const float*)d_in[8];
    const float* bu4 = (const float*)d_in[9];
    float* out = (float*)d_out;

    const i64 WHC = (i64)WH * CD;   // 1,048,576
    const i64 GM  = (i64)WH * WH;   // 16,777,216
    const i64 CC  = (i64)CD * CD;

    // workspace carve — ~139 MB (proven-safe: 204.5 MB ran previously)
    auto al = [](size_t x) { return (x + 255) & ~(size_t)255; };
    char* p = (char*)d_ws; size_t off = 0;
    auto carve = [&](size_t bytes) { void* r = p + off; off += al(bytes); return r; };
    unsigned short* Gb    = (unsigned short*)carve((size_t)GM * 2);      // 33.6 MB  gs f16
    unsigned short* skthi = (unsigned short*)carve((size_t)4 * WHC * 2);
    unsigned short* sktlo = (unsigned short*)carve((size_t)4 * WHC * 2);
    unsigned short* refhi = (unsigned short*)carve((size_t)4 * WHC * 2);
    unsigned short* reflo = (unsigned short*)carve((size_t)4 * WHC * 2);
    unsigned short* ghi   = (unsigned short*)carve((size_t)4 * WHC * 2);
    unsigned short* glo   = (unsigned short*)carve((size_t)4 * WHC * 2); // 6x8.39 MB
    unsigned short* axthi = (unsigned short*)carve((size_t)4 * WHC * 2);
    unsigned short* axtlo = (unsigned short*)carve((size_t)4 * WHC * 2); // 16.8 MB
    float* ob             = (float*)carve((size_t)WH * 4);
    float* partb          = (float*)carve((size_t)64 * WH * 4);          // 1.05 MB
    float2* rowPb         = (float2*)carve((size_t)64 * WH * 8);         // 2.1 MB (64 halves)
    unsigned short* Wthi  = (unsigned short*)carve((size_t)4 * CC * 2);
    unsigned short* Wtlo  = (unsigned short*)carve((size_t)4 * CC * 2);
    float* Pw             = (float*)carve((size_t)8 * WHC * 4);          // 33.6 MB f32

    dim3 thr(256), ttr(32, 8);
    // batched transposes: one dispatch for skt+ref (8 z), one for the 4 weights
    {
        TransArgs ta{};
        for (int b = 0; b < 4; ++b) {
            ta.src[b] = skt + (i64)b * WHC;     ta.src[b + 4] = ref + (i64)b * WHC;
            ta.dhi[b] = skthi + (i64)b * WHC;   ta.dhi[b + 4] = refhi + (i64)b * WHC;
            ta.dlo[b] = sktlo + (i64)b * WHC;   ta.dlo[b + 4] = reflo + (i64)b * WHC;
        }
        k_transN<<<dim3(WH / 32, CD / 32, 8), ttr, 0, stream>>>(ta, CD, WH);
        TransArgs tw{};
        const float* ws[4] = { Wa3, Wu3, Wa4, Wu4 };
        for (int i = 0; i < 4; ++i) {
            tw.src[i] = ws[i];
            tw.dhi[i] = Wthi + (i64)i * CC;
            tw.dlo[i] = Wtlo + (i64)i * CC;
        }
        k_transN<<<dim3(CD / 32, CD / 32, 4), ttr, 0, stream>>>(tw, CD, CD);
    }

    // FULL3 = 1: stage A (split attn path, emits gen split); 0: stage B (hi-only attn)
    auto stage = [&](const unsigned short* shi, const unsigned short* slo,
                     const unsigned short* mhi, const unsigned short* mlo,
                     int widx, const float* ba, const float* bu, float* outf,
                     unsigned short* ohi, unsigned short* olo, int FULL3) {
        // ax = relu(msg @ Wa + ba), stored transposed as f16 split (all 4 batches)
        if (FULL3)
            k_gemm<1, 1><<<dim3(CD / 128, WH / 128, 4), thr, 0, stream>>>(
                mhi, mlo, CD, WHC, Wthi + (i64)widx * CC, Wtlo + (i64)widx * CC, CD, 0,
                nullptr, axthi, axtlo, WH, WHC, CD, ba, nullptr, nullptr);
        else
            k_gemm<1, 0><<<dim3(CD / 128, WH / 128, 4), thr, 0, stream>>>(
                mhi, nullptr, CD, WHC, Wthi + (i64)widx * CC, nullptr, CD, 0,
                nullptr, axthi, axtlo, WH, WHC, CD, ba, nullptr, nullptr);
        // r = relu(src @ Wu + bu) + src  -> outf (all 4 batches)
        if (FULL3)
            k_gemm<2, 1><<<dim3(CD / 128, WH / 128, 4), thr, 0, stream>>>(
                shi, slo, CD, WHC, Wthi + (i64)(widx + 1) * CC, Wtlo + (i64)(widx + 1) * CC, CD, 0,
                outf, nullptr, nullptr, CD, WHC, CD, bu, shi, slo);
        else
            k_gemm<2, 0><<<dim3(CD / 128, WH / 128, 4), thr, 0, stream>>>(
                shi, nullptr, CD, WHC, Wthi + (i64)(widx + 1) * CC, nullptr, CD, 0,
                outf, nullptr, nullptr, CD, WHC, CD, bu, shi, slo);
        for (int b = 0; b < 4; ++b) {
            // logits -> gs f16 (scaled sqrt-domain) + rowP (64 halves)
            k_logits<<<dim3(WH / 128, WH / 128, 1), thr, 0, stream>>>(
                shi + (i64)b * WHC, slo + (i64)b * WHC,
                mhi + (i64)b * WHC, mlo + (i64)b * WHC, Gb, rowPb);
            // o-finalize + column partials (factor-mul, no exp in inner loop)
            k_colpart<<<dim3(WH / 256, WH / 64, 1), thr, 0, stream>>>(Gb, rowPb, ob, partb);
            // attention (colS in-prologue; split-K 8, f32 partial stores)
            if (FULL3)
                k_attn<1><<<dim3(CD / 128, WH / 128, 8), thr, 0, stream>>>(
                    Gb, ob, rowPb, partb, axthi + (i64)b * WHC, axtlo + (i64)b * WHC, Pw);
            else
                k_attn<0><<<dim3(CD / 128, WH / 128, 8), thr, 0, stream>>>(
                    Gb, ob, rowPb, partb, axthi + (i64)b * WHC, nullptr, Pw);
            // outf[b] += sum_z P[z]  (+ f16 split of gen for stage A)
            if (ohi)
                k_red<1><<<dim3((unsigned)(WHC / 1024)), thr, 0, stream>>>(
                    Pw, outf + (i64)b * WHC, ohi + (i64)b * WHC, olo + (i64)b * WHC);
            else
                k_red<0><<<dim3((unsigned)(WHC / 1024)), thr, 0, stream>>>(
                    Pw, outf + (i64)b * WHC, nullptr, nullptr);
        }
    };

    // stage A: src = skt, msg = ref -> gen (accumulated in d_out, split to ghi/glo)
    stage(skthi, sktlo, refhi, reflo, 0, ba3, bu3, out, ghi, glo, 1);
    // stage B: src = msg = gen -> final output (overwrites d_out)
    stage(ghi, glo, ghi, glo, 2, ba4, bu4, out, nullptr, nullptr, 0);
}

// Round 7
// 1055.105 us; speedup vs baseline: 1.1469x; 1.0599x over previous
//
#include <hip/hip_runtime.h>
#include <cstdint>
#include <cstddef>

#define WH 4096
#define CD 256
typedef long long i64;

typedef __attribute__((ext_vector_type(8))) _Float16 f16x8;
typedef __attribute__((ext_vector_type(4))) float f32x4;

#define AS1 __attribute__((address_space(1)))
#define AS3 __attribute__((address_space(3)))

__device__ __forceinline__ unsigned short f2h(float f) {
    _Float16 h = (_Float16)f;
    return __builtin_bit_cast(unsigned short, h);
}
__device__ __forceinline__ float h2f(unsigned short u) {
    return (float)__builtin_bit_cast(_Float16, u);
}
__device__ __forceinline__ void ld16_lds(const void* g, void* l) {
    __builtin_amdgcn_global_load_lds((AS1 void*)g, (AS3 void*)l, 16, 0, 0);
}

// -------- batched transpose f32 -> f16 split; per-z pre-offset pointers
struct TransArgs {
    const float* src[8];
    unsigned short* dhi[8];
    unsigned short* dlo[8];
};
__global__ __launch_bounds__(256) void k_transN(TransArgs ta, int RR, int CC) {
    __shared__ float t[32][33];
    const float* s = ta.src[blockIdx.z];
    unsigned short* dhi = ta.dhi[blockIdx.z];
    unsigned short* dlo = ta.dlo[blockIdx.z];
    const int c0 = blockIdx.x * 32, r0 = blockIdx.y * 32;
    const int tx = threadIdx.x, ty = threadIdx.y;
#pragma unroll
    for (int i = 0; i < 4; ++i)
        t[ty + i * 8][tx] = s[(i64)(r0 + ty + i * 8) * CC + c0 + tx];
    __syncthreads();
#pragma unroll
    for (int i = 0; i < 4; ++i) {
        const i64 idx = (i64)(c0 + ty + i * 8) * RR + r0 + tx;
        const float v = t[tx][ty + i * 8];
        const unsigned short hi = f2h(v);
        dhi[idx] = hi;
        dlo[idx] = f2h(v - h2f(hi));
    }
}

// -------- NT GEMM, f16. SPLIT3=1: 3 MFMA products; SPLIT3=0: hi only.
// MODE 1: bias+relu, store transposed f16-split (ax -> axt hi/lo)
// MODE 2: bias+relu, add split residual, f32 store (r -> outf)
template <int MODE, int SPLIT3>
__global__ __launch_bounds__(256) void k_gemm(
    const unsigned short* __restrict__ A, const unsigned short* __restrict__ A2, int lda, i64 sA,
    const unsigned short* __restrict__ B, const unsigned short* __restrict__ B2, int ldb, i64 sB,
    float* __restrict__ Cf, unsigned short* __restrict__ Chi, unsigned short* __restrict__ Clo,
    int ldc, i64 sC, int K,
    const float* __restrict__ bias,
    const unsigned short* __restrict__ addh, const unsigned short* __restrict__ addl) {
    __shared__ __align__(16) short lA[SPLIT3 ? 8192 : 4096];
    __shared__ __align__(16) short lB[SPLIT3 ? 8192 : 4096];
    const int z = blockIdx.z;
    A += (i64)z * sA; B += (i64)z * sB;
    if constexpr (SPLIT3) { A2 += (i64)z * sA; B2 += (i64)z * sB; }

    const int tid = threadIdx.x;
    const int w = tid >> 6, l = tid & 63;
    const int wm = w >> 1, wn = w & 1;
    const int bm = blockIdx.y * 128, bn = blockIdx.x * 128;
    const int l15 = l & 15, lq = l >> 4;

    f32x4 acc[4][4] = {};

    for (int kt = 0; kt < K; kt += 32) {
        __syncthreads();
#pragma unroll
        for (int rr = 0; rr < 2; ++rr) {
            const int r = w + rr * 4;          // region 0..7
            const int kb = r >> 1, mh = r & 1;
            const int row = mh * 64 + l;
            const i64 ao = (i64)(bm + row) * lda + kt + kb * 8;
            const i64 bo = (i64)(bn + row) * ldb + kt + kb * 8;
            ld16_lds(A + ao, (char*)lA + r * 1024);
            ld16_lds(B + bo, (char*)lB + r * 1024);
            if constexpr (SPLIT3) {
                ld16_lds(A2 + ao, (char*)lA + 8192 + r * 1024);
                ld16_lds(B2 + bo, (char*)lB + 8192 + r * 1024);
            }
        }
        __syncthreads();
        f16x8 ah[4], bh[4], al[4], bl[4];
#pragma unroll
        for (int i = 0; i < 4; ++i) {
            const int ia = (lq * 128 + wm * 64 + i * 16 + l15) * 8;
            const int ib = (lq * 128 + wn * 64 + i * 16 + l15) * 8;
            ah[i] = *(const f16x8*)(lA + ia);
            bh[i] = *(const f16x8*)(lB + ib);
            if constexpr (SPLIT3) {
                al[i] = *(const f16x8*)(lA + 4096 + ia);
                bl[i] = *(const f16x8*)(lB + 4096 + ib);
            }
        }
#pragma unroll
        for (int i = 0; i < 4; ++i)
#pragma unroll
            for (int j = 0; j < 4; ++j) {
                acc[i][j] = __builtin_amdgcn_mfma_f32_16x16x32_f16(ah[i], bh[j], acc[i][j], 0, 0, 0);
                if constexpr (SPLIT3) {
                    acc[i][j] = __builtin_amdgcn_mfma_f32_16x16x32_f16(ah[i], bl[j], acc[i][j], 0, 0, 0);
                    acc[i][j] = __builtin_amdgcn_mfma_f32_16x16x32_f16(al[i], bh[j], acc[i][j], 0, 0, 0);
                }
            }
    }

#pragma unroll
    for (int i = 0; i < 4; ++i)
#pragma unroll
        for (int j = 0; j < 4; ++j) {
            const int n = bn + wn * 64 + j * 16 + l15;
            const int m0 = bm + wm * 64 + i * 16 + lq * 4;
            const float bv = bias[n];
            if constexpr (MODE == 1) {
                unsigned short hv[4], lv[4];
#pragma unroll
                for (int r = 0; r < 4; ++r) {
                    const float v = fmaxf(acc[i][j][r] + bv, 0.f);
                    hv[r] = f2h(v);
                    lv[r] = f2h(v - h2f(hv[r]));
                }
                const i64 tb = (i64)z * sC + (i64)n * ldc + m0;
                *(ushort4*)(Chi + tb) = make_ushort4(hv[0], hv[1], hv[2], hv[3]);
                *(ushort4*)(Clo + tb) = make_ushort4(lv[0], lv[1], lv[2], lv[3]);
            } else {  // MODE 2
#pragma unroll
                for (int r = 0; r < 4; ++r) {
                    const i64 idx = (i64)z * sC + (i64)(m0 + r) * ldc + n;
                    float v = fmaxf(acc[i][j][r] + bv, 0.f);
                    v += h2f(addh[idx]) + h2f(addl[idx]);
                    Cf[idx] = v;
                }
            }
        }
}

// -------- logits GEMM (split-3), 256x128 tile -> gs = 256*exp((L-m_half)/2) f16, plus rowP.
// Wider tile: 96 MFMA per thread-K-step vs 48 at the same 2-barrier cost (amortizes the
// structural stall that binds this kernel at ~17% MfmaUtil).
// rowP layout: [64 half-tiles][WH rows] of (m_half, expsum_half); half = blockIdx.x*2 + wn.
__global__ __launch_bounds__(256, 2) void k_logits(
    const unsigned short* __restrict__ A, const unsigned short* __restrict__ A2,
    const unsigned short* __restrict__ B, const unsigned short* __restrict__ B2,
    unsigned short* __restrict__ G, float2* __restrict__ rowP) {
    __shared__ __align__(16) short lA[16384];  // 32 KB: A-hi @0, A-lo @+8192 shorts
    __shared__ __align__(16) short lB[8192];   // 16 KB: B-hi @0, B-lo @+4096 shorts
    const int tid = threadIdx.x;
    const int w = tid >> 6, l = tid & 63;
    const int wm = w >> 1, wn = w & 1;
    const int bm = blockIdx.y * 256, bn = blockIdx.x * 128;
    const int l15 = l & 15, lq = l >> 4;

    f32x4 acc[8][4] = {};

    for (int kt = 0; kt < CD; kt += 32) {
        __syncthreads();
#pragma unroll
        for (int rr = 0; rr < 12; ++rr) {
            const int r = w + rr * 4;          // 0..47 (wave-uniform branch below)
            if (r < 32) {                       // A: 16 hi + 16 lo regions (256 rows)
                const int ra = r & 15;
                const int kb = ra >> 2, nh = ra & 3;
                const i64 ao = (i64)(bm + nh * 64 + l) * CD + kt + kb * 8;
                if (r < 16) ld16_lds(A + ao, (char*)lA + ra * 1024);
                else        ld16_lds(A2 + ao, (char*)lA + 16384 + ra * 1024);
            } else {                            // B: 8 hi + 8 lo regions (128 rows)
                const int rb = r & 7;
                const int kb = rb >> 1, mh = rb & 1;
                const i64 bo = (i64)(bn + mh * 64 + l) * CD + kt + kb * 8;
                if (r < 40) ld16_lds(B + bo, (char*)lB + rb * 1024);
                else        ld16_lds(B2 + bo, (char*)lB + 8192 + rb * 1024);
            }
        }
        __syncthreads();
        f16x8 bh[4], bl[4];
#pragma unroll
        for (int j = 0; j < 4; ++j) {
            const int ib = (lq * 128 + wn * 64 + j * 16 + l15) * 8;
            bh[j] = *(const f16x8*)(lB + ib);
            bl[j] = *(const f16x8*)(lB + 4096 + ib);
        }
#pragma unroll
        for (int i = 0; i < 8; ++i) {
            const int ia = (lq * 256 + wm * 128 + i * 16 + l15) * 8;
            const f16x8 ah = *(const f16x8*)(lA + ia);
            const f16x8 al = *(const f16x8*)(lA + 8192 + ia);
#pragma unroll
            for (int j = 0; j < 4; ++j) {
                acc[i][j] = __builtin_amdgcn_mfma_f32_16x16x32_f16(ah, bh[j], acc[i][j], 0, 0, 0);
                acc[i][j] = __builtin_amdgcn_mfma_f32_16x16x32_f16(ah, bl[j], acc[i][j], 0, 0, 0);
                acc[i][j] = __builtin_amdgcn_mfma_f32_16x16x32_f16(al, bh[j], acc[i][j], 0, 0, 0);
            }
        }
    }

    // epilogue: per (row, wn-half): m over 64 cols, gs f16 store, exact f32 expsum, rowP store
#pragma unroll
    for (int i = 0; i < 8; ++i)
#pragma unroll
        for (int r = 0; r < 4; ++r) {
            const int grow = bm + wm * 128 + i * 16 + lq * 4 + r;
            float m = fmaxf(fmaxf(acc[i][0][r], acc[i][1][r]), fmaxf(acc[i][2][r], acc[i][3][r]));
            m = fmaxf(m, __shfl_xor(m, 1));
            m = fmaxf(m, __shfl_xor(m, 2));
            m = fmaxf(m, __shfl_xor(m, 4));
            m = fmaxf(m, __shfl_xor(m, 8));
            float s = 0.f;
#pragma unroll
            for (int j = 0; j < 4; ++j) {
                const float es = __expf((acc[i][j][r] - m) * 0.5f);
                s += es * es;   // exact exp(L-m) rowsum in f32
                G[(i64)grow * WH + bn + wn * 64 + j * 16 + l15] = f2h(es * 256.f);
            }
            s += __shfl_xor(s, 1); s += __shfl_xor(s, 2);
            s += __shfl_xor(s, 4); s += __shfl_xor(s, 8);
            if (l15 == 0)
                rowP[(i64)(blockIdx.x * 2 + wn) * WH + grow] = make_float2(m, s);
        }
}

// -------- fused: merge rowP (64 halves) -> o; col partials = sum gs^2 * factor.
// factor = exp(m_half - o)/65536 undoes the sqrt-domain scaling. grid (16, 64).
__global__ __launch_bounds__(256) void k_colpart(const unsigned short* __restrict__ G,
                                                 const float2* __restrict__ rowP,
                                                 float* __restrict__ o,
                                                 float* __restrict__ part) {
    __shared__ float os[64];
    __shared__ float fl[4][64];
    const int t = threadIdx.x;
    const int r0 = blockIdx.y * 64;
    if (t < 64) {
        float M = -3.4e38f, S = 0.f;
        for (int x = 0; x < 64; ++x) {
            const float2 p = rowP[(i64)x * WH + r0 + t];
            const float nm = fmaxf(M, p.x);
            S = S * __expf(M - nm) + p.y * __expf(p.x - nm);
            M = nm;
        }
        const float ov = M + __logf(S);
        os[t] = ov;
        if (blockIdx.x == 0) o[r0 + t] = ov;
    }
    __syncthreads();
    {   // 256 factors: (r, jt) for this block's 4 column half-tiles
        const int jt = t & 3, r = t >> 2;
        fl[jt][r] = __expf(rowP[(i64)(blockIdx.x * 4 + jt) * WH + r0 + r].x - os[r])
                  * (1.f / 65536.f);
    }
    __syncthreads();
    const int j = blockIdx.x * 256 + t;
    const int jt = t >> 6;
    float ps = 0.f;
#pragma unroll 4
    for (int r = 0; r < 64; ++r) {
        const float gv = h2f(G[(i64)(r0 + r) * WH + j]);
        ps += gv * gv * fl[jt][r];
    }
    part[(i64)blockIdx.y * WH + j] = ps;
}

// -------- fused attention: P = [gs^2 * exp(m_half-o)/65536 * colS_j] @ axt^T, f16 partials.
// colS computed in-prologue from part. No exp in the inner loop (3 muls per element).
// FULL=1: split A and B (3 MFMA); FULL=0: hi-only. grid (2, 32, 8): z = k-chunk of 512.
template <int FULL>
__global__ __launch_bounds__(256) void k_attn(
    const unsigned short* __restrict__ G, const float* __restrict__ o,
    const float2* __restrict__ rowP, const float* __restrict__ part,
    const unsigned short* __restrict__ Bh, const unsigned short* __restrict__ Bl,
    unsigned short* __restrict__ Pw) {
    __shared__ __align__(16) short lL[4096];   // 8 KB: gs 128 rows x 32 k
    __shared__ __align__(16) short lBh[4096];  // 8 KB
    __shared__ __align__(16) short lBl[FULL ? 4096 : 8];
    __shared__ float lS[512];
    const int tid = threadIdx.x;
    const int w = tid >> 6, l = tid & 63;
    const int wm = w >> 1, wn = w & 1;
    const int bm = blockIdx.y * 128, bn = blockIdx.x * 128;
    const int l15 = l & 15, lq = l >> 4;
    const i64 koff = (i64)blockIdx.z * 512;

    // colS for this k-chunk from part (same summation order as the old k_colreduce)
    {
        float C0 = 0.f, C1 = 0.f;
#pragma unroll 4
        for (int p = 0; p < 64; ++p) {
            C0 += part[(i64)p * WH + koff + tid];
            C1 += part[(i64)p * WH + koff + 256 + tid];
        }
        lS[tid] = 1.f / fmaxf(C0, 1e-12f);
        lS[tid + 256] = 1.f / fmaxf(C1, 1e-12f);
    }
    float o4[4];
#pragma unroll
    for (int i = 0; i < 4; ++i) o4[i] = o[bm + wm * 64 + i * 16 + l15];

    float fi[4];
    f32x4 acc[4][4] = {};
    for (int kt = 0; kt < 512; kt += 32) {
        __syncthreads();
#pragma unroll
        for (int rr = 0; rr < 2; ++rr) {
            const int r = w + rr * 4;          // region 0..7 (1 KB each) — gs staging
            const int kb = r >> 1, mh = r & 1;
            ld16_lds(G + (i64)(bm + mh * 64 + l) * WH + koff + kt + kb * 8,
                     (char*)lL + r * 1024);
        }
#pragma unroll
        for (int rr = 0; rr < 2; ++rr) {
            const int r = w + rr * 4;          // region 0..7
            const int kb = r >> 1, mh = r & 1;
            const i64 bo = (i64)(bn + mh * 64 + l) * WH + koff + kt + kb * 8;
            ld16_lds(Bh + bo, (char*)lBh + r * 1024);
            if constexpr (FULL) ld16_lds(Bl + bo, (char*)lBl + r * 1024);
        }
        // per-(row, 64-k-half) factor exp(m_half - o)/65536: refresh every other K-step
        if ((kt & 32) == 0) {
            const i64 half = (koff + kt) >> 6;
#pragma unroll
            for (int i = 0; i < 4; ++i)
                fi[i] = __expf(rowP[half * WH + bm + wm * 64 + i * 16 + l15].x - o4[i])
                      * (1.f / 65536.f);
        }
        __syncthreads();
        float sv[8];
        *(float4*)(sv)     = *(const float4*)(lS + kt + lq * 8);
        *(float4*)(sv + 4) = *(const float4*)(lS + kt + lq * 8 + 4);
        f16x8 bh[4], bl[4];
#pragma unroll
        for (int j = 0; j < 4; ++j) {
            const int ib = (lq * 128 + wn * 64 + j * 16 + l15) * 8;
            bh[j] = *(const f16x8*)(lBh + ib);
            if constexpr (FULL) bl[j] = *(const f16x8*)(lBl + ib);
        }
#pragma unroll
        for (int i = 0; i < 4; ++i) {
            const f16x8 graw = *(const f16x8*)(lL + (lq * 128 + wm * 64 + i * 16 + l15) * 8);
            const float fi_ = fi[i];
            f16x8 ah, al;
#pragma unroll
            for (int e = 0; e < 8; ++e) {
                const float gv = (float)graw[e];
                const float a = gv * gv * fi_ * sv[e];
                const _Float16 hh = (_Float16)a;
                ah[e] = hh;
                if constexpr (FULL) al[e] = (_Float16)(a - (float)hh);
            }
#pragma unroll
            for (int j = 0; j < 4; ++j) {
                acc[i][j] = __builtin_amdgcn_mfma_f32_16x16x32_f16(ah, bh[j], acc[i][j], 0, 0, 0);
                if constexpr (FULL) {
                    acc[i][j] = __builtin_amdgcn_mfma_f32_16x16x32_f16(ah, bl[j], acc[i][j], 0, 0, 0);
                    acc[i][j] = __builtin_amdgcn_mfma_f32_16x16x32_f16(al, bh[j], acc[i][j], 0, 0, 0);
                }
            }
        }
    }
    unsigned short* P = Pw + (i64)blockIdx.z * ((i64)WH * CD);
#pragma unroll
    for (int i = 0; i < 4; ++i)
#pragma unroll
        for (int j = 0; j < 4; ++j) {
            const int n = bn + wn * 64 + j * 16 + l15;
            const int m0 = bm + wm * 64 + i * 16 + lq * 4;
#pragma unroll
            for (int r = 0; r < 4; ++r)
                P[(i64)(m0 + r) * CD + n] = f2h(acc[i][j][r]);
        }
}

// -------- reduce 8 f16 split-K partials into outf (holds r); optionally emit f16 split of result
template <int SPLIT>
__global__ __launch_bounds__(256) void k_red(const unsigned short* __restrict__ Pw,
                                             float* __restrict__ outp,
                                             unsigned short* __restrict__ hi,
                                             unsigned short* __restrict__ lo) {
    const i64 i = ((i64)blockIdx.x * 256 + threadIdx.x) * 4;
    float4 a = *(const float4*)(outp + i);
#pragma unroll
    for (int z = 0; z < 8; ++z) {
        const ushort4 p = *(const ushort4*)(Pw + (i64)z * ((i64)WH * CD) + i);
        a.x += h2f(p.x); a.y += h2f(p.y); a.z += h2f(p.z); a.w += h2f(p.w);
    }
    *(float4*)(outp + i) = a;
    if constexpr (SPLIT) {
        ushort4 h, l2;
        h.x = f2h(a.x); l2.x = f2h(a.x - h2f(h.x));
        h.y = f2h(a.y); l2.y = f2h(a.y - h2f(h.y));
        h.z = f2h(a.z); l2.z = f2h(a.z - h2f(h.z));
        h.w = f2h(a.w); l2.w = f2h(a.w - h2f(h.w));
        *(ushort4*)(hi + i) = h;
        *(ushort4*)(lo + i) = l2;
    }
}

extern "C" void kernel_launch(void* const* d_in, const int* in_sizes, int n_in,
                              void* d_out, int out_size, void* d_ws, size_t ws_size,
                              hipStream_t stream) {
    (void)in_sizes; (void)n_in; (void)out_size; (void)ws_size;
    const float* skt = (const float*)d_in[0];
    const float* ref = (const float*)d_in[1];
    const float* Wa3 = (const float*)d_in[2];
    const float* ba3 = (const float*)d_in[3];
    const float* Wu3 = (const float*)d_in[4];
    const float* bu3 = (const float*)d_in[5];
    const float* Wa4 = (const float*)d_in[6];
    const float* ba4 = (const float*)d_in[7];
    const float* Wu4 = (const float*)d_in[8];
    const float* bu4 = (const float*)d_in[9];
    float* out = (float*)d_out;

    const i64 WHC = (i64)WH * CD;   // 1,048,576
    const i64 GM  = (i64)WH * WH;   // 16,777,216
    const i64 CC  = (i64)CD * CD;

    // workspace carve — ~122 MB (proven-safe: 204.5 MB ran previously)
    auto al = [](size_t x) { return (x + 255) & ~(size_t)255; };
    char* p = (char*)d_ws; size_t off = 0;
    auto carve = [&](size_t bytes) { void* r = p + off; off += al(bytes); return r; };
    unsigned short* Gb    = (unsigned short*)carve((size_t)GM * 2);      // 33.6 MB  gs f16
    unsigned short* skthi = (unsigned short*)carve((size_t)4 * WHC * 2);
    unsigned short* sktlo = (unsigned short*)carve((size_t)4 * WHC * 2);
    unsigned short* refhi = (unsigned short*)carve((size_t)4 * WHC * 2);
    unsigned short* reflo = (unsigned short*)carve((size_t)4 * WHC * 2);
    unsigned short* ghi   = (unsigned short*)carve((size_t)4 * WHC * 2);
    unsigned short* glo   = (unsigned short*)carve((size_t)4 * WHC * 2); // 6x8.39 MB
    unsigned short* axthi = (unsigned short*)carve((size_t)4 * WHC * 2);
    unsigned short* axtlo = (unsigned short*)carve((size_t)4 * WHC * 2); // 16.8 MB
    float* ob             = (float*)carve((size_t)WH * 4);
    float* partb          = (float*)carve((size_t)64 * WH * 4);          // 1.05 MB
    float2* rowPb         = (float2*)carve((size_t)64 * WH * 8);         // 2.1 MB (64 halves)
    unsigned short* Wthi  = (unsigned short*)carve((size_t)4 * CC * 2);
    unsigned short* Wtlo  = (unsigned short*)carve((size_t)4 * CC * 2);
    unsigned short* Pw    = (unsigned short*)carve((size_t)8 * WHC * 2); // 16.8 MB f16

    dim3 thr(256), ttr(32, 8);
    // batched transposes: one dispatch for skt+ref (8 z), one for the 4 weights
    {
        TransArgs ta{};
        for (int b = 0; b < 4; ++b) {
            ta.src[b] = skt + (i64)b * WHC;     ta.src[b + 4] = ref + (i64)b * WHC;
            ta.dhi[b] = skthi + (i64)b * WHC;   ta.dhi[b + 4] = refhi + (i64)b * WHC;
            ta.dlo[b] = sktlo + (i64)b * WHC;   ta.dlo[b + 4] = reflo + (i64)b * WHC;
        }
        k_transN<<<dim3(WH / 32, CD / 32, 8), ttr, 0, stream>>>(ta, CD, WH);
        TransArgs tw{};
        const float* ws[4] = { Wa3, Wu3, Wa4, Wu4 };
        for (int i = 0; i < 4; ++i) {
            tw.src[i] = ws[i];
            tw.dhi[i] = Wthi + (i64)i * CC;
            tw.dlo[i] = Wtlo + (i64)i * CC;
        }
        k_transN<<<dim3(CD / 32, CD / 32, 4), ttr, 0, stream>>>(tw, CD, CD);
    }

    // FULL3 = 1: stage A (split attn path, emits gen split); 0: stage B (hi-only attn)
    auto stage = [&](const unsigned short* shi, const unsigned short* slo,
                     const unsigned short* mhi, const unsigned short* mlo,
                     int widx, const float* ba, const float* bu, float* outf,
                     unsigned short* ohi, unsigned short* olo, int FULL3) {
        // ax = relu(msg @ Wa + ba), stored transposed as f16 split (all 4 batches)
        if (FULL3)
            k_gemm<1, 1><<<dim3(CD / 128, WH / 128, 4), thr, 0, stream>>>(
                mhi, mlo, CD, WHC, Wthi + (i64)widx * CC, Wtlo + (i64)widx * CC, CD, 0,
                nullptr, axthi, axtlo, WH, WHC, CD, ba, nullptr, nullptr);
        else
            k_gemm<1, 0><<<dim3(CD / 128, WH / 128, 4), thr, 0, stream>>>(
                mhi, nullptr, CD, WHC, Wthi + (i64)widx * CC, nullptr, CD, 0,
                nullptr, axthi, axtlo, WH, WHC, CD, ba, nullptr, nullptr);
        // r = relu(src @ Wu + bu) + src  -> outf (all 4 batches)
        if (FULL3)
            k_gemm<2, 1><<<dim3(CD / 128, WH / 128, 4), thr, 0, stream>>>(
                shi, slo, CD, WHC, Wthi + (i64)(widx + 1) * CC, Wtlo + (i64)(widx + 1) * CC, CD, 0,
                outf, nullptr, nullptr, CD, WHC, CD, bu, shi, slo);
        else
            k_gemm<2, 0><<<dim3(CD / 128, WH / 128, 4), thr, 0, stream>>>(
                shi, nullptr, CD, WHC, Wthi + (i64)(widx + 1) * CC, nullptr, CD, 0,
                outf, nullptr, nullptr, CD, WHC, CD, bu, shi, slo);
        for (int b = 0; b < 4; ++b) {
            // logits -> gs f16 (scaled sqrt-domain), 256x128 tiles + rowP (64 halves)
            k_logits<<<dim3(WH / 128, WH / 256, 1), thr, 0, stream>>>(
                shi + (i64)b * WHC, slo + (i64)b * WHC,
                mhi + (i64)b * WHC, mlo + (i64)b * WHC, Gb, rowPb);
            // o-finalize + column partials (factor-mul, no exp in inner loop)
            k_colpart<<<dim3(WH / 256, WH / 64, 1), thr, 0, stream>>>(Gb, rowPb, ob, partb);
            // attention (colS in-prologue; split-K 8, f16 partial stores)
            if (FULL3)
                k_attn<1><<<dim3(CD / 128, WH / 128, 8), thr, 0, stream>>>(
                    Gb, ob, rowPb, partb, axthi + (i64)b * WHC, axtlo + (i64)b * WHC, Pw);
            else
                k_attn<0><<<dim3(CD / 128, WH / 128, 8), thr, 0, stream>>>(
                    Gb, ob, rowPb, partb, axthi + (i64)b * WHC, nullptr, Pw);
            // outf[b] += sum_z P[z]  (+ f16 split of gen for stage A)
            if (ohi)
                k_red<1><<<dim3((unsigned)(WHC / 1024)), thr, 0, stream>>>(
                    Pw, outf + (i64)b * WHC, ohi + (i64)b * WHC, olo + (i64)b * WHC);
            else
                k_red<0><<<dim3((unsigned)(WHC / 1024)), thr, 0, stream>>>(
                    Pw, outf + (i64)b * WHC, nullptr, nullptr);
        }
    };

    // stage A: src = skt, msg = ref -> gen (accumulated in d_out, split to ghi/glo)
    stage(skthi, sktlo, refhi, reflo, 0, ba3, bu3, out, ghi, glo, 1);
    // stage B: src = msg = gen -> final output (overwrites d_out)
    stage(ghi, glo, ghi, glo, 2, ba4, bu4, out, nullptr, nullptr, 0);
}

// Round 8
// 959.811 us; speedup vs baseline: 1.2608x; 1.0993x over previous
//
#include <hip/hip_runtime.h>
#include <cstdint>
#include <cstddef>

#define WH 4096
#define CD 256
typedef long long i64;

typedef __attribute__((ext_vector_type(8))) _Float16 f16x8;
typedef __attribute__((ext_vector_type(4))) float f32x4;

#define AS1 __attribute__((address_space(1)))
#define AS3 __attribute__((address_space(3)))

__device__ __forceinline__ unsigned short f2h(float f) {
    _Float16 h = (_Float16)f;
    return __builtin_bit_cast(unsigned short, h);
}
__device__ __forceinline__ float h2f(unsigned short u) {
    return (float)__builtin_bit_cast(_Float16, u);
}
__device__ __forceinline__ void ld16_lds(const void* g, void* l) {
    __builtin_amdgcn_global_load_lds((AS1 void*)g, (AS3 void*)l, 16, 0, 0);
}

// -------- batched transpose f32 -> f16 split; per-z pre-offset pointers
struct TransArgs {
    const float* src[8];
    unsigned short* dhi[8];
    unsigned short* dlo[8];
};
__global__ __launch_bounds__(256) void k_transN(TransArgs ta, int RR, int CC) {
    __shared__ float t[32][33];
    const float* s = ta.src[blockIdx.z];
    unsigned short* dhi = ta.dhi[blockIdx.z];
    unsigned short* dlo = ta.dlo[blockIdx.z];
    const int c0 = blockIdx.x * 32, r0 = blockIdx.y * 32;
    const int tx = threadIdx.x, ty = threadIdx.y;
#pragma unroll
    for (int i = 0; i < 4; ++i)
        t[ty + i * 8][tx] = s[(i64)(r0 + ty + i * 8) * CC + c0 + tx];
    __syncthreads();
#pragma unroll
    for (int i = 0; i < 4; ++i) {
        const i64 idx = (i64)(c0 + ty + i * 8) * RR + r0 + tx;
        const float v = t[tx][ty + i * 8];
        const unsigned short hi = f2h(v);
        dhi[idx] = hi;
        dlo[idx] = f2h(v - h2f(hi));
    }
}

// -------- NT GEMM, f16. SPLIT3=1: 3 MFMA products; SPLIT3=0: hi only.
// MODE 1: bias+relu, store transposed f16-split (ax -> axt hi/lo)
// MODE 2: bias+relu, add split residual, f32 store (r -> outf)
template <int MODE, int SPLIT3>
__global__ __launch_bounds__(256) void k_gemm(
    const unsigned short* __restrict__ A, const unsigned short* __restrict__ A2, int lda, i64 sA,
    const unsigned short* __restrict__ B, const unsigned short* __restrict__ B2, int ldb, i64 sB,
    float* __restrict__ Cf, unsigned short* __restrict__ Chi, unsigned short* __restrict__ Clo,
    int ldc, i64 sC, int K,
    const float* __restrict__ bias,
    const unsigned short* __restrict__ addh, const unsigned short* __restrict__ addl) {
    __shared__ __align__(16) short lA[SPLIT3 ? 8192 : 4096];
    __shared__ __align__(16) short lB[SPLIT3 ? 8192 : 4096];
    const int z = blockIdx.z;
    A += (i64)z * sA; B += (i64)z * sB;
    if constexpr (SPLIT3) { A2 += (i64)z * sA; B2 += (i64)z * sB; }

    const int tid = threadIdx.x;
    const int w = tid >> 6, l = tid & 63;
    const int wm = w >> 1, wn = w & 1;
    const int bm = blockIdx.y * 128, bn = blockIdx.x * 128;
    const int l15 = l & 15, lq = l >> 4;

    f32x4 acc[4][4] = {};

    for (int kt = 0; kt < K; kt += 32) {
        __syncthreads();
#pragma unroll
        for (int rr = 0; rr < 2; ++rr) {
            const int r = w + rr * 4;          // region 0..7
            const int kb = r >> 1, mh = r & 1;
            const int row = mh * 64 + l;
            const i64 ao = (i64)(bm + row) * lda + kt + kb * 8;
            const i64 bo = (i64)(bn + row) * ldb + kt + kb * 8;
            ld16_lds(A + ao, (char*)lA + r * 1024);
            ld16_lds(B + bo, (char*)lB + r * 1024);
            if constexpr (SPLIT3) {
                ld16_lds(A2 + ao, (char*)lA + 8192 + r * 1024);
                ld16_lds(B2 + bo, (char*)lB + 8192 + r * 1024);
            }
        }
        __syncthreads();
        f16x8 ah[4], bh[4], al[4], bl[4];
#pragma unroll
        for (int i = 0; i < 4; ++i) {
            const int ia = (lq * 128 + wm * 64 + i * 16 + l15) * 8;
            const int ib = (lq * 128 + wn * 64 + i * 16 + l15) * 8;
            ah[i] = *(const f16x8*)(lA + ia);
            bh[i] = *(const f16x8*)(lB + ib);
            if constexpr (SPLIT3) {
                al[i] = *(const f16x8*)(lA + 4096 + ia);
                bl[i] = *(const f16x8*)(lB + 4096 + ib);
            }
        }
#pragma unroll
        for (int i = 0; i < 4; ++i)
#pragma unroll
            for (int j = 0; j < 4; ++j) {
                acc[i][j] = __builtin_amdgcn_mfma_f32_16x16x32_f16(ah[i], bh[j], acc[i][j], 0, 0, 0);
                if constexpr (SPLIT3) {
                    acc[i][j] = __builtin_amdgcn_mfma_f32_16x16x32_f16(ah[i], bl[j], acc[i][j], 0, 0, 0);
                    acc[i][j] = __builtin_amdgcn_mfma_f32_16x16x32_f16(al[i], bh[j], acc[i][j], 0, 0, 0);
                }
            }
    }

#pragma unroll
    for (int i = 0; i < 4; ++i)
#pragma unroll
        for (int j = 0; j < 4; ++j) {
            const int n = bn + wn * 64 + j * 16 + l15;
            const int m0 = bm + wm * 64 + i * 16 + lq * 4;
            const float bv = bias[n];
            if constexpr (MODE == 1) {
                unsigned short hv[4], lv[4];
#pragma unroll
                for (int r = 0; r < 4; ++r) {
                    const float v = fmaxf(acc[i][j][r] + bv, 0.f);
                    hv[r] = f2h(v);
                    lv[r] = f2h(v - h2f(hv[r]));
                }
                const i64 tb = (i64)z * sC + (i64)n * ldc + m0;
                *(ushort4*)(Chi + tb) = make_ushort4(hv[0], hv[1], hv[2], hv[3]);
                *(ushort4*)(Clo + tb) = make_ushort4(lv[0], lv[1], lv[2], lv[3]);
            } else {  // MODE 2
#pragma unroll
                for (int r = 0; r < 4; ++r) {
                    const i64 idx = (i64)z * sC + (i64)(m0 + r) * ldc + n;
                    float v = fmaxf(acc[i][j][r] + bv, 0.f);
                    v += h2f(addh[idx]) + h2f(addl[idx]);
                    Cf[idx] = v;
                }
            }
        }
}

// -------- logits GEMM (split-3), 256x128 tile, BATCH-PAIR z -> gs = 256*exp((L-m_half)/2)
// f16, plus rowP. z = blockIdx.z selects batch within the pair (decorrelated co-residency).
// rowP layout: [64 half-tiles][WH rows] of (m_half, expsum_half); half = blockIdx.x*2 + wn.
__global__ __launch_bounds__(256, 2) void k_logits(
    const unsigned short* __restrict__ A, const unsigned short* __restrict__ A2,
    const unsigned short* __restrict__ B, const unsigned short* __restrict__ B2,
    unsigned short* __restrict__ G, float2* __restrict__ rowP, i64 sAB) {
    __shared__ __align__(16) short lA[16384];  // 32 KB: A-hi @0, A-lo @+8192 shorts
    __shared__ __align__(16) short lB[8192];   // 16 KB: B-hi @0, B-lo @+4096 shorts
    const int z = blockIdx.z;
    A += (i64)z * sAB; A2 += (i64)z * sAB;
    B += (i64)z * sAB; B2 += (i64)z * sAB;
    G += (i64)z * ((i64)WH * WH);
    rowP += (i64)z * (64 * (i64)WH);
    const int tid = threadIdx.x;
    const int w = tid >> 6, l = tid & 63;
    const int wm = w >> 1, wn = w & 1;
    const int bm = blockIdx.y * 256, bn = blockIdx.x * 128;
    const int l15 = l & 15, lq = l >> 4;

    f32x4 acc[8][4] = {};

    for (int kt = 0; kt < CD; kt += 32) {
        __syncthreads();
#pragma unroll
        for (int rr = 0; rr < 12; ++rr) {
            const int r = w + rr * 4;          // 0..47 (wave-uniform branch below)
            if (r < 32) {                       // A: 16 hi + 16 lo regions (256 rows)
                const int ra = r & 15;
                const int kb = ra >> 2, nh = ra & 3;
                const i64 ao = (i64)(bm + nh * 64 + l) * CD + kt + kb * 8;
                if (r < 16) ld16_lds(A + ao, (char*)lA + ra * 1024);
                else        ld16_lds(A2 + ao, (char*)lA + 16384 + ra * 1024);
            } else {                            // B: 8 hi + 8 lo regions (128 rows)
                const int rb = r & 7;
                const int kb = rb >> 1, mh = rb & 1;
                const i64 bo = (i64)(bn + mh * 64 + l) * CD + kt + kb * 8;
                if (r < 40) ld16_lds(B + bo, (char*)lB + rb * 1024);
                else        ld16_lds(B2 + bo, (char*)lB + 8192 + rb * 1024);
            }
        }
        __syncthreads();
        f16x8 bh[4], bl[4];
#pragma unroll
        for (int j = 0; j < 4; ++j) {
            const int ib = (lq * 128 + wn * 64 + j * 16 + l15) * 8;
            bh[j] = *(const f16x8*)(lB + ib);
            bl[j] = *(const f16x8*)(lB + 4096 + ib);
        }
#pragma unroll
        for (int i = 0; i < 8; ++i) {
            const int ia = (lq * 256 + wm * 128 + i * 16 + l15) * 8;
            const f16x8 ah = *(const f16x8*)(lA + ia);
            const f16x8 al = *(const f16x8*)(lA + 8192 + ia);
#pragma unroll
            for (int j = 0; j < 4; ++j) {
                acc[i][j] = __builtin_amdgcn_mfma_f32_16x16x32_f16(ah, bh[j], acc[i][j], 0, 0, 0);
                acc[i][j] = __builtin_amdgcn_mfma_f32_16x16x32_f16(ah, bl[j], acc[i][j], 0, 0, 0);
                acc[i][j] = __builtin_amdgcn_mfma_f32_16x16x32_f16(al, bh[j], acc[i][j], 0, 0, 0);
            }
        }
    }

    // epilogue: per (row, wn-half): m over 64 cols, gs f16 store, exact f32 expsum, rowP store
#pragma unroll
    for (int i = 0; i < 8; ++i)
#pragma unroll
        for (int r = 0; r < 4; ++r) {
            const int grow = bm + wm * 128 + i * 16 + lq * 4 + r;
            float m = fmaxf(fmaxf(acc[i][0][r], acc[i][1][r]), fmaxf(acc[i][2][r], acc[i][3][r]));
            m = fmaxf(m, __shfl_xor(m, 1));
            m = fmaxf(m, __shfl_xor(m, 2));
            m = fmaxf(m, __shfl_xor(m, 4));
            m = fmaxf(m, __shfl_xor(m, 8));
            float s = 0.f;
#pragma unroll
            for (int j = 0; j < 4; ++j) {
                const float es = __expf((acc[i][j][r] - m) * 0.5f);
                s += es * es;   // exact exp(L-m) rowsum in f32
                G[(i64)grow * WH + bn + wn * 64 + j * 16 + l15] = f2h(es * 256.f);
            }
            s += __shfl_xor(s, 1); s += __shfl_xor(s, 2);
            s += __shfl_xor(s, 4); s += __shfl_xor(s, 8);
            if (l15 == 0)
                rowP[(i64)(blockIdx.x * 2 + wn) * WH + grow] = make_float2(m, s);
        }
}

// -------- fused: merge rowP (64 halves) -> o; col partials = sum gs^2 * factor.
// factor = exp(m_half - o)/65536 undoes the sqrt-domain scaling. grid (16, 64, 2=pair).
__global__ __launch_bounds__(256) void k_colpart(const unsigned short* __restrict__ G,
                                                 const float2* __restrict__ rowP,
                                                 float* __restrict__ o,
                                                 float* __restrict__ part) {
    __shared__ float os[64];
    __shared__ float fl[4][64];
    const int z = blockIdx.z;
    G += (i64)z * ((i64)WH * WH);
    rowP += (i64)z * (64 * (i64)WH);
    o += (i64)z * WH;
    part += (i64)z * (64 * (i64)WH);
    const int t = threadIdx.x;
    const int r0 = blockIdx.y * 64;
    if (t < 64) {
        float M = -3.4e38f, S = 0.f;
        for (int x = 0; x < 64; ++x) {
            const float2 p = rowP[(i64)x * WH + r0 + t];
            const float nm = fmaxf(M, p.x);
            S = S * __expf(M - nm) + p.y * __expf(p.x - nm);
            M = nm;
        }
        const float ov = M + __logf(S);
        os[t] = ov;
        if (blockIdx.x == 0) o[r0 + t] = ov;
    }
    __syncthreads();
    {   // 256 factors: (r, jt) for this block's 4 column half-tiles
        const int jt = t & 3, r = t >> 2;
        fl[jt][r] = __expf(rowP[(i64)(blockIdx.x * 4 + jt) * WH + r0 + r].x - os[r])
                  * (1.f / 65536.f);
    }
    __syncthreads();
    const int j = blockIdx.x * 256 + t;
    const int jt = t >> 6;
    float ps = 0.f;
#pragma unroll 4
    for (int r = 0; r < 64; ++r) {
        const float gv = h2f(G[(i64)(r0 + r) * WH + j]);
        ps += gv * gv * fl[jt][r];
    }
    part[(i64)blockIdx.y * WH + j] = ps;
}

// -------- fused attention: P = [gs^2 * exp(m_half-o)/65536 * colS_j] @ axt^T, f16 partials.
// colS computed in-prologue from part. grid (2, 32, 16): z = chunk(0..7) + 8*batch-in-pair.
template <int FULL>
__global__ __launch_bounds__(256) void k_attn(
    const unsigned short* __restrict__ G, const float* __restrict__ o,
    const float2* __restrict__ rowP, const float* __restrict__ part,
    const unsigned short* __restrict__ Bh, const unsigned short* __restrict__ Bl,
    unsigned short* __restrict__ Pw) {
    __shared__ __align__(16) short lL[4096];   // 8 KB: gs 128 rows x 32 k
    __shared__ __align__(16) short lBh[4096];  // 8 KB
    __shared__ __align__(16) short lBl[FULL ? 4096 : 8];
    __shared__ float lS[512];
    const int zb = blockIdx.z >> 3;            // batch within pair
    const int zc = blockIdx.z & 7;             // k-chunk
    G += (i64)zb * ((i64)WH * WH);
    o += (i64)zb * WH;
    rowP += (i64)zb * (64 * (i64)WH);
    part += (i64)zb * (64 * (i64)WH);
    Bh += (i64)zb * ((i64)WH * CD);
    if constexpr (FULL) Bl += (i64)zb * ((i64)WH * CD);
    Pw += (i64)zb * (8 * (i64)WH * CD);
    const int tid = threadIdx.x;
    const int w = tid >> 6, l = tid & 63;
    const int wm = w >> 1, wn = w & 1;
    const int bm = blockIdx.y * 128, bn = blockIdx.x * 128;
    const int l15 = l & 15, lq = l >> 4;
    const i64 koff = (i64)zc * 512;

    // colS for this k-chunk from part (same summation order as the old k_colreduce)
    {
        float C0 = 0.f, C1 = 0.f;
#pragma unroll 4
        for (int p = 0; p < 64; ++p) {
            C0 += part[(i64)p * WH + koff + tid];
            C1 += part[(i64)p * WH + koff + 256 + tid];
        }
        lS[tid] = 1.f / fmaxf(C0, 1e-12f);
        lS[tid + 256] = 1.f / fmaxf(C1, 1e-12f);
    }
    float o4[4];
#pragma unroll
    for (int i = 0; i < 4; ++i) o4[i] = o[bm + wm * 64 + i * 16 + l15];

    float fi[4];
    f32x4 acc[4][4] = {};
    for (int kt = 0; kt < 512; kt += 32) {
        __syncthreads();
#pragma unroll
        for (int rr = 0; rr < 2; ++rr) {
            const int r = w + rr * 4;          // region 0..7 (1 KB each) — gs staging
            const int kb = r >> 1, mh = r & 1;
            ld16_lds(G + (i64)(bm + mh * 64 + l) * WH + koff + kt + kb * 8,
                     (char*)lL + r * 1024);
        }
#pragma unroll
        for (int rr = 0; rr < 2; ++rr) {
            const int r = w + rr * 4;          // region 0..7
            const int kb = r >> 1, mh = r & 1;
            const i64 bo = (i64)(bn + mh * 64 + l) * WH + koff + kt + kb * 8;
            ld16_lds(Bh + bo, (char*)lBh + r * 1024);
            if constexpr (FULL) ld16_lds(Bl + bo, (char*)lBl + r * 1024);
        }
        // per-(row, 64-k-half) factor exp(m_half - o)/65536: refresh every other K-step
        if ((kt & 32) == 0) {
            const i64 half = (koff + kt) >> 6;
#pragma unroll
            for (int i = 0; i < 4; ++i)
                fi[i] = __expf(rowP[half * WH + bm + wm * 64 + i * 16 + l15].x - o4[i])
                      * (1.f / 65536.f);
        }
        __syncthreads();
        float sv[8];
        *(float4*)(sv)     = *(const float4*)(lS + kt + lq * 8);
        *(float4*)(sv + 4) = *(const float4*)(lS + kt + lq * 8 + 4);
        f16x8 bh[4], bl[4];
#pragma unroll
        for (int j = 0; j < 4; ++j) {
            const int ib = (lq * 128 + wn * 64 + j * 16 + l15) * 8;
            bh[j] = *(const f16x8*)(lBh + ib);
            if constexpr (FULL) bl[j] = *(const f16x8*)(lBl + ib);
        }
#pragma unroll
        for (int i = 0; i < 4; ++i) {
            const f16x8 graw = *(const f16x8*)(lL + (lq * 128 + wm * 64 + i * 16 + l15) * 8);
            const float fi_ = fi[i];
            f16x8 ah, al;
#pragma unroll
            for (int e = 0; e < 8; ++e) {
                const float gv = (float)graw[e];
                const float a = gv * gv * fi_ * sv[e];
                const _Float16 hh = (_Float16)a;
                ah[e] = hh;
                if constexpr (FULL) al[e] = (_Float16)(a - (float)hh);
            }
#pragma unroll
            for (int j = 0; j < 4; ++j) {
                acc[i][j] = __builtin_amdgcn_mfma_f32_16x16x32_f16(ah, bh[j], acc[i][j], 0, 0, 0);
                if constexpr (FULL) {
                    acc[i][j] = __builtin_amdgcn_mfma_f32_16x16x32_f16(ah, bl[j], acc[i][j], 0, 0, 0);
                    acc[i][j] = __builtin_amdgcn_mfma_f32_16x16x32_f16(al, bh[j], acc[i][j], 0, 0, 0);
                }
            }
        }
    }
    unsigned short* P = Pw + (i64)zc * ((i64)WH * CD);
#pragma unroll
    for (int i = 0; i < 4; ++i)
#pragma unroll
        for (int j = 0; j < 4; ++j) {
            const int n = bn + wn * 64 + j * 16 + l15;
            const int m0 = bm + wm * 64 + i * 16 + lq * 4;
#pragma unroll
            for (int r = 0; r < 4; ++r)
                P[(i64)(m0 + r) * CD + n] = f2h(acc[i][j][r]);
        }
}

// -------- reduce 8 f16 split-K partials into outf; grid (WHC/1024, 2=pair)
template <int SPLIT>
__global__ __launch_bounds__(256) void k_red(const unsigned short* __restrict__ Pw,
                                             float* __restrict__ outp,
                                             unsigned short* __restrict__ hi,
                                             unsigned short* __restrict__ lo) {
    const int b = blockIdx.y;
    Pw += (i64)b * (8 * (i64)WH * CD);
    outp += (i64)b * ((i64)WH * CD);
    if constexpr (SPLIT) {
        hi += (i64)b * ((i64)WH * CD);
        lo += (i64)b * ((i64)WH * CD);
    }
    const i64 i = ((i64)blockIdx.x * 256 + threadIdx.x) * 4;
    float4 a = *(const float4*)(outp + i);
#pragma unroll
    for (int z = 0; z < 8; ++z) {
        const ushort4 p = *(const ushort4*)(Pw + (i64)z * ((i64)WH * CD) + i);
        a.x += h2f(p.x); a.y += h2f(p.y); a.z += h2f(p.z); a.w += h2f(p.w);
    }
    *(float4*)(outp + i) = a;
    if constexpr (SPLIT) {
        ushort4 h, l2;
        h.x = f2h(a.x); l2.x = f2h(a.x - h2f(h.x));
        h.y = f2h(a.y); l2.y = f2h(a.y - h2f(h.y));
        h.z = f2h(a.z); l2.z = f2h(a.z - h2f(h.z));
        h.w = f2h(a.w); l2.w = f2h(a.w - h2f(h.w));
        *(ushort4*)(hi + i) = h;
        *(ushort4*)(lo + i) = l2;
    }
}

extern "C" void kernel_launch(void* const* d_in, const int* in_sizes, int n_in,
                              void* d_out, int out_size, void* d_ws, size_t ws_size,
                              hipStream_t stream) {
    (void)in_sizes; (void)n_in; (void)out_size; (void)ws_size;
    const float* skt = (const float*)d_in[0];
    const float* ref = (const float*)d_in[1];
    const float* Wa3 = (const float*)d_in[2];
    const float* ba3 = (const float*)d_in[3];
    const float* Wu3 = (const float*)d_in[4];
    const float* bu3 = (const float*)d_in[5];
    const float* Wa4 = (const float*)d_in[6];
    const float* ba4 = (const float*)d_in[7];
    const float* Wu4 = (const float*)d_in[8];
    const float* bu4 = (const float*)d_in[9];
    float* out = (float*)d_out;

    const i64 WHC = (i64)WH * CD;   // 1,048,576
    const i64 GM  = (i64)WH * WH;   // 16,777,216
    const i64 CC  = (i64)CD * CD;

    // workspace carve — ~175 MB (proven-safe: 204.5 MB ran previously)
    auto al = [](size_t x) { return (x + 255) & ~(size_t)255; };
    char* p = (char*)d_ws; size_t off = 0;
    auto carve = [&](size_t bytes) { void* r = p + off; off += al(bytes); return r; };
    unsigned short* Gb    = (unsigned short*)carve((size_t)2 * GM * 2);  // 67.1 MB  gs f16 x pair
    unsigned short* skthi = (unsigned short*)carve((size_t)4 * WHC * 2);
    unsigned short* sktlo = (unsigned short*)carve((size_t)4 * WHC * 2);
    unsigned short* refhi = (unsigned short*)carve((size_t)4 * WHC * 2);
    unsigned short* reflo = (unsigned short*)carve((size_t)4 * WHC * 2);
    unsigned short* ghi   = (unsigned short*)carve((size_t)4 * WHC * 2);
    unsigned short* glo   = (unsigned short*)carve((size_t)4 * WHC * 2); // 6x8.39 MB
    unsigned short* axthi = (unsigned short*)carve((size_t)4 * WHC * 2);
    unsigned short* axtlo = (unsigned short*)carve((size_t)4 * WHC * 2); // 16.8 MB
    float* ob             = (float*)carve((size_t)2 * WH * 4);
    float* partb          = (float*)carve((size_t)2 * 64 * WH * 4);      // 2.1 MB
    float2* rowPb         = (float2*)carve((size_t)2 * 64 * WH * 8);     // 4.2 MB
    unsigned short* Wthi  = (unsigned short*)carve((size_t)4 * CC * 2);
    unsigned short* Wtlo  = (unsigned short*)carve((size_t)4 * CC * 2);
    unsigned short* Pw    = (unsigned short*)carve((size_t)2 * 8 * WHC * 2); // 33.6 MB

    dim3 thr(256), ttr(32, 8);
    // batched transposes: one dispatch for skt+ref (8 z), one for the 4 weights
    {
        TransArgs ta{};
        for (int b = 0; b < 4; ++b) {
            ta.src[b] = skt + (i64)b * WHC;     ta.src[b + 4] = ref + (i64)b * WHC;
            ta.dhi[b] = skthi + (i64)b * WHC;   ta.dhi[b + 4] = refhi + (i64)b * WHC;
            ta.dlo[b] = sktlo + (i64)b * WHC;   ta.dlo[b + 4] = reflo + (i64)b * WHC;
        }
        k_transN<<<dim3(WH / 32, CD / 32, 8), ttr, 0, stream>>>(ta, CD, WH);
        TransArgs tw{};
        const float* ws[4] = { Wa3, Wu3, Wa4, Wu4 };
        for (int i = 0; i < 4; ++i) {
            tw.src[i] = ws[i];
            tw.dhi[i] = Wthi + (i64)i * CC;
            tw.dlo[i] = Wtlo + (i64)i * CC;
        }
        k_transN<<<dim3(CD / 32, CD / 32, 4), ttr, 0, stream>>>(tw, CD, CD);
    }

    // FULL3 = 1: stage A (split attn path, emits gen split); 0: stage B (hi-only attn)
    auto stage = [&](const unsigned short* shi, const unsigned short* slo,
                     const unsigned short* mhi, const unsigned short* mlo,
                     int widx, const float* ba, const float* bu, float* outf,
                     unsigned short* ohi, unsigned short* olo, int FULL3) {
        // ax = relu(msg @ Wa + ba), stored transposed as f16 split (all 4 batches)
        if (FULL3)
            k_gemm<1, 1><<<dim3(CD / 128, WH / 128, 4), thr, 0, stream>>>(
                mhi, mlo, CD, WHC, Wthi + (i64)widx * CC, Wtlo + (i64)widx * CC, CD, 0,
                nullptr, axthi, axtlo, WH, WHC, CD, ba, nullptr, nullptr);
        else
            k_gemm<1, 0><<<dim3(CD / 128, WH / 128, 4), thr, 0, stream>>>(
                mhi, nullptr, CD, WHC, Wthi + (i64)widx * CC, nullptr, CD, 0,
                nullptr, axthi, axtlo, WH, WHC, CD, ba, nullptr, nullptr);
        // r = relu(src @ Wu + bu) + src  -> outf (all 4 batches)
        if (FULL3)
            k_gemm<2, 1><<<dim3(CD / 128, WH / 128, 4), thr, 0, stream>>>(
                shi, slo, CD, WHC, Wthi + (i64)(widx + 1) * CC, Wtlo + (i64)(widx + 1) * CC, CD, 0,
                outf, nullptr, nullptr, CD, WHC, CD, bu, shi, slo);
        else
            k_gemm<2, 0><<<dim3(CD / 128, WH / 128, 4), thr, 0, stream>>>(
                shi, nullptr, CD, WHC, Wthi + (i64)(widx + 1) * CC, nullptr, CD, 0,
                outf, nullptr, nullptr, CD, WHC, CD, bu, shi, slo);
        for (int pb = 0; pb < 2; ++pb) {
            const i64 bo = (i64)(2 * pb) * WHC;
            // logits (pair) -> gs f16 (scaled sqrt-domain) + rowP
            k_logits<<<dim3(WH / 128, WH / 256, 2), thr, 0, stream>>>(
                shi + bo, slo + bo, mhi + bo, mlo + bo, Gb, rowPb, WHC);
            // o-finalize + column partials (pair)
            k_colpart<<<dim3(WH / 256, WH / 64, 2), thr, 0, stream>>>(Gb, rowPb, ob, partb);
            // attention (pair; colS in-prologue; split-K 8, f16 partial stores)
            if (FULL3)
                k_attn<1><<<dim3(CD / 128, WH / 128, 16), thr, 0, stream>>>(
                    Gb, ob, rowPb, partb, axthi + bo, axtlo + bo, Pw);
            else
                k_attn<0><<<dim3(CD / 128, WH / 128, 16), thr, 0, stream>>>(
                    Gb, ob, rowPb, partb, axthi + bo, nullptr, Pw);
            // outf += sum_z P[z]  (+ f16 split of gen for stage A)  (pair)
            if (ohi)
                k_red<1><<<dim3((unsigned)(WHC / 1024), 2), thr, 0, stream>>>(
                    Pw, outf + bo, ohi + bo, olo + bo);
            else
                k_red<0><<<dim3((unsigned)(WHC / 1024), 2), thr, 0, stream>>>(
                    Pw, outf + bo, nullptr, nullptr);
        }
    };

    // stage A: src = skt, msg = ref -> gen (accumulated in d_out, split to ghi/glo)
    stage(skthi, sktlo, refhi, reflo, 0, ba3, bu3, out, ghi, glo, 1);
    // stage B: src = msg = gen -> final output (overwrites d_out)
    stage(ghi, glo, ghi, glo, 2, ba4, bu4, out, nullptr, nullptr, 0);
}

// Round 11
// 933.815 us; speedup vs baseline: 1.2958x; 1.0278x over previous
//
#include <hip/hip_runtime.h>
#include <cstdint>
#include <cstddef>

#define WH 4096
#define CD 256
typedef long long i64;

typedef __attribute__((ext_vector_type(8))) _Float16 f16x8;
typedef __attribute__((ext_vector_type(4))) float f32x4;

#define AS1 __attribute__((address_space(1)))
#define AS3 __attribute__((address_space(3)))

__device__ __forceinline__ unsigned short f2h(float f) {
    _Float16 h = (_Float16)f;
    return __builtin_bit_cast(unsigned short, h);
}
__device__ __forceinline__ float h2f(unsigned short u) {
    return (float)__builtin_bit_cast(_Float16, u);
}
__device__ __forceinline__ void ld16_lds(const void* g, void* l) {
    __builtin_amdgcn_global_load_lds((AS1 void*)g, (AS3 void*)l, 16, 0, 0);
}

// -------- batched transpose f32 -> f16 split; per-z pre-offset pointers
struct TransArgs {
    const float* src[8];
    unsigned short* dhi[8];
    unsigned short* dlo[8];
};
__global__ __launch_bounds__(256) void k_transN(TransArgs ta, int RR, int CC) {
    __shared__ float t[32][33];
    const float* s = ta.src[blockIdx.z];
    unsigned short* dhi = ta.dhi[blockIdx.z];
    unsigned short* dlo = ta.dlo[blockIdx.z];
    const int c0 = blockIdx.x * 32, r0 = blockIdx.y * 32;
    const int tx = threadIdx.x, ty = threadIdx.y;
#pragma unroll
    for (int i = 0; i < 4; ++i)
        t[ty + i * 8][tx] = s[(i64)(r0 + ty + i * 8) * CC + c0 + tx];
    __syncthreads();
#pragma unroll
    for (int i = 0; i < 4; ++i) {
        const i64 idx = (i64)(c0 + ty + i * 8) * RR + r0 + tx;
        const float v = t[tx][ty + i * 8];
        const unsigned short hi = f2h(v);
        dhi[idx] = hi;
        dlo[idx] = f2h(v - h2f(hi));
    }
}

// -------- merged ax/r GEMM: grid (2, 32, 8). z<4: ax = relu(msg@Wa+ba) -> axt f16-split
// (transposed store). z>=4: r = relu(src@Wu+bu) + src -> outf f32. One dispatch = 512
// blocks = 2/CU (each half alone was 256 blocks = 1/CU, occupancy-starved).
// FIXED (r9/r10 bug): residual read uses base pointers Shi/Slo with the single batch
// offset inside idx — previously addh was pre-offset by zb*WHC AND idx included zb*WHC.
template <int SPLIT3>
__global__ __launch_bounds__(256) void k_gemm12(
    const unsigned short* __restrict__ Shi, const unsigned short* __restrict__ Slo,
    const unsigned short* __restrict__ Mhi, const unsigned short* __restrict__ Mlo,
    const unsigned short* __restrict__ WAh, const unsigned short* __restrict__ WAl,
    const unsigned short* __restrict__ WUh, const unsigned short* __restrict__ WUl,
    const float* __restrict__ ba, const float* __restrict__ bu,
    unsigned short* __restrict__ axh, unsigned short* __restrict__ axl,
    float* __restrict__ outf) {
    __shared__ __align__(16) short lA[SPLIT3 ? 8192 : 4096];
    __shared__ __align__(16) short lB[SPLIT3 ? 8192 : 4096];
    const int mode = blockIdx.z >> 2;          // 0: ax, 1: r
    const int zb = blockIdx.z & 3;             // batch
    const i64 WHC = (i64)WH * CD;
    const unsigned short* A  = (mode ? Shi : Mhi) + (i64)zb * WHC;
    const unsigned short* A2 = SPLIT3 ? ((mode ? Slo : Mlo) + (i64)zb * WHC) : nullptr;
    const unsigned short* B  = mode ? WUh : WAh;
    const unsigned short* B2 = SPLIT3 ? (mode ? WUl : WAl) : nullptr;
    const float* bias = mode ? bu : ba;

    const int tid = threadIdx.x;
    const int w = tid >> 6, l = tid & 63;
    const int wm = w >> 1, wn = w & 1;
    const int bm = blockIdx.y * 128, bn = blockIdx.x * 128;
    const int l15 = l & 15, lq = l >> 4;

    f32x4 acc[4][4] = {};

    for (int kt = 0; kt < CD; kt += 32) {
        __syncthreads();
#pragma unroll
        for (int rr = 0; rr < 2; ++rr) {
            const int r = w + rr * 4;          // region 0..7
            const int kb = r >> 1, mh = r & 1;
            const int row = mh * 64 + l;
            const i64 ao = (i64)(bm + row) * CD + kt + kb * 8;
            const i64 bo = (i64)(bn + row) * CD + kt + kb * 8;
            ld16_lds(A + ao, (char*)lA + r * 1024);
            ld16_lds(B + bo, (char*)lB + r * 1024);
            if constexpr (SPLIT3) {
                ld16_lds(A2 + ao, (char*)lA + 8192 + r * 1024);
                ld16_lds(B2 + bo, (char*)lB + 8192 + r * 1024);
            }
        }
        __syncthreads();
        f16x8 ah[4], bh[4], al[4], bl[4];
#pragma unroll
        for (int i = 0; i < 4; ++i) {
            const int ia = (lq * 128 + wm * 64 + i * 16 + l15) * 8;
            const int ib = (lq * 128 + wn * 64 + i * 16 + l15) * 8;
            ah[i] = *(const f16x8*)(lA + ia);
            bh[i] = *(const f16x8*)(lB + ib);
            if constexpr (SPLIT3) {
                al[i] = *(const f16x8*)(lA + 4096 + ia);
                bl[i] = *(const f16x8*)(lB + 4096 + ib);
            }
        }
#pragma unroll
        for (int i = 0; i < 4; ++i)
#pragma unroll
            for (int j = 0; j < 4; ++j) {
                acc[i][j] = __builtin_amdgcn_mfma_f32_16x16x32_f16(ah[i], bh[j], acc[i][j], 0, 0, 0);
                if constexpr (SPLIT3) {
                    acc[i][j] = __builtin_amdgcn_mfma_f32_16x16x32_f16(ah[i], bl[j], acc[i][j], 0, 0, 0);
                    acc[i][j] = __builtin_amdgcn_mfma_f32_16x16x32_f16(al[i], bh[j], acc[i][j], 0, 0, 0);
                }
            }
    }

#pragma unroll
    for (int i = 0; i < 4; ++i)
#pragma unroll
        for (int j = 0; j < 4; ++j) {
            const int n = bn + wn * 64 + j * 16 + l15;
            const int m0 = bm + wm * 64 + i * 16 + lq * 4;
            const float bv = bias[n];
            if (mode == 0) {                   // ax -> transposed f16-split
                unsigned short hv[4], lv[4];
#pragma unroll
                for (int r = 0; r < 4; ++r) {
                    const float v = fmaxf(acc[i][j][r] + bv, 0.f);
                    hv[r] = f2h(v);
                    lv[r] = f2h(v - h2f(hv[r]));
                }
                const i64 tb = (i64)zb * WHC + (i64)n * WH + m0;
                *(ushort4*)(axh + tb) = make_ushort4(hv[0], hv[1], hv[2], hv[3]);
                *(ushort4*)(axl + tb) = make_ushort4(lv[0], lv[1], lv[2], lv[3]);
            } else {                           // r -> f32 + split residual
#pragma unroll
                for (int r = 0; r < 4; ++r) {
                    const i64 idx = (i64)zb * WHC + (i64)(m0 + r) * CD + n;
                    float v = fmaxf(acc[i][j][r] + bv, 0.f);
                    v += h2f(Shi[idx]) + h2f(Slo[idx]);   // single batch offset (in idx)
                    outf[idx] = v;
                }
            }
        }
}

// -------- logits GEMM (split-3), 256x128 tile, BATCH-PAIR z -> gs = 256*exp((L-m_half)/2)
// f16, plus rowP. z = blockIdx.z selects batch within the pair (decorrelated co-residency).
// rowP layout: [64 half-tiles][WH rows] of (m_half, expsum_half); half = blockIdx.x*2 + wn.
__global__ __launch_bounds__(256, 2) void k_logits(
    const unsigned short* __restrict__ A, const unsigned short* __restrict__ A2,
    const unsigned short* __restrict__ B, const unsigned short* __restrict__ B2,
    unsigned short* __restrict__ G, float2* __restrict__ rowP, i64 sAB) {
    __shared__ __align__(16) short lA[16384];  // 32 KB: A-hi @0, A-lo @+8192 shorts
    __shared__ __align__(16) short lB[8192];   // 16 KB: B-hi @0, B-lo @+4096 shorts
    const int z = blockIdx.z;
    A += (i64)z * sAB; A2 += (i64)z * sAB;
    B += (i64)z * sAB; B2 += (i64)z * sAB;
    G += (i64)z * ((i64)WH * WH);
    rowP += (i64)z * (64 * (i64)WH);
    const int tid = threadIdx.x;
    const int w = tid >> 6, l = tid & 63;
    const int wm = w >> 1, wn = w & 1;
    const int bm = blockIdx.y * 256, bn = blockIdx.x * 128;
    const int l15 = l & 15, lq = l >> 4;

    f32x4 acc[8][4] = {};

    for (int kt = 0; kt < CD; kt += 32) {
        __syncthreads();
#pragma unroll
        for (int rr = 0; rr < 12; ++rr) {
            const int r = w + rr * 4;          // 0..47 (wave-uniform branch below)
            if (r < 32) {                       // A: 16 hi + 16 lo regions (256 rows)
                const int ra = r & 15;
                const int kb = ra >> 2, nh = ra & 3;
                const i64 ao = (i64)(bm + nh * 64 + l) * CD + kt + kb * 8;
                if (r < 16) ld16_lds(A + ao, (char*)lA + ra * 1024);
                else        ld16_lds(A2 + ao, (char*)lA + 16384 + ra * 1024);
            } else {                            // B: 8 hi + 8 lo regions (128 rows)
                const int rb = r & 7;
                const int kb = rb >> 1, mh = rb & 1;
                const i64 bo = (i64)(bn + mh * 64 + l) * CD + kt + kb * 8;
                if (r < 40) ld16_lds(B + bo, (char*)lB + rb * 1024);
                else        ld16_lds(B2 + bo, (char*)lB + 8192 + rb * 1024);
            }
        }
        __syncthreads();
        f16x8 bh[4], bl[4];
#pragma unroll
        for (int j = 0; j < 4; ++j) {
            const int ib = (lq * 128 + wn * 64 + j * 16 + l15) * 8;
            bh[j] = *(const f16x8*)(lB + ib);
            bl[j] = *(const f16x8*)(lB + 4096 + ib);
        }
#pragma unroll
        for (int i = 0; i < 8; ++i) {
            const int ia = (lq * 256 + wm * 128 + i * 16 + l15) * 8;
            const f16x8 ah = *(const f16x8*)(lA + ia);
            const f16x8 al = *(const f16x8*)(lA + 8192 + ia);
#pragma unroll
            for (int j = 0; j < 4; ++j) {
                acc[i][j] = __builtin_amdgcn_mfma_f32_16x16x32_f16(ah, bh[j], acc[i][j], 0, 0, 0);
                acc[i][j] = __builtin_amdgcn_mfma_f32_16x16x32_f16(ah, bl[j], acc[i][j], 0, 0, 0);
                acc[i][j] = __builtin_amdgcn_mfma_f32_16x16x32_f16(al, bh[j], acc[i][j], 0, 0, 0);
            }
        }
    }

    // epilogue: per (row, wn-half): m over 64 cols, gs f16 store, exact f32 expsum, rowP store
#pragma unroll
    for (int i = 0; i < 8; ++i)
#pragma unroll
        for (int r = 0; r < 4; ++r) {
            const int grow = bm + wm * 128 + i * 16 + lq * 4 + r;
            float m = fmaxf(fmaxf(acc[i][0][r], acc[i][1][r]), fmaxf(acc[i][2][r], acc[i][3][r]));
            m = fmaxf(m, __shfl_xor(m, 1));
            m = fmaxf(m, __shfl_xor(m, 2));
            m = fmaxf(m, __shfl_xor(m, 4));
            m = fmaxf(m, __shfl_xor(m, 8));
            float s = 0.f;
#pragma unroll
            for (int j = 0; j < 4; ++j) {
                const float es = __expf((acc[i][j][r] - m) * 0.5f);
                s += es * es;   // exact exp(L-m) rowsum in f32
                G[(i64)grow * WH + bn + wn * 64 + j * 16 + l15] = f2h(es * 256.f);
            }
            s += __shfl_xor(s, 1); s += __shfl_xor(s, 2);
            s += __shfl_xor(s, 4); s += __shfl_xor(s, 8);
            if (l15 == 0)
                rowP[(i64)(blockIdx.x * 2 + wn) * WH + grow] = make_float2(m, s);
        }
}

// -------- fused: merge rowP (64 halves) -> o; col partials = sum gs^2 * factor.
// factor = exp(m_half - o)/65536 undoes the sqrt-domain scaling. grid (16, 64, 2=pair).
__global__ __launch_bounds__(256) void k_colpart(const unsigned short* __restrict__ G,
                                                 const float2* __restrict__ rowP,
                                                 float* __restrict__ o,
                                                 float* __restrict__ part) {
    __shared__ float os[64];
    __shared__ float fl[4][64];
    const int z = blockIdx.z;
    G += (i64)z * ((i64)WH * WH);
    rowP += (i64)z * (64 * (i64)WH);
    o += (i64)z * WH;
    part += (i64)z * (64 * (i64)WH);
    const int t = threadIdx.x;
    const int r0 = blockIdx.y * 64;
    if (t < 64) {
        float M = -3.4e38f, S = 0.f;
        for (int x = 0; x < 64; ++x) {
            const float2 p = rowP[(i64)x * WH + r0 + t];
            const float nm = fmaxf(M, p.x);
            S = S * __expf(M - nm) + p.y * __expf(p.x - nm);
            M = nm;
        }
        const float ov = M + __logf(S);
        os[t] = ov;
        if (blockIdx.x == 0) o[r0 + t] = ov;
    }
    __syncthreads();
    {   // 256 factors: (r, jt) for this block's 4 column half-tiles
        const int jt = t & 3, r = t >> 2;
        fl[jt][r] = __expf(rowP[(i64)(blockIdx.x * 4 + jt) * WH + r0 + r].x - os[r])
                  * (1.f / 65536.f);
    }
    __syncthreads();
    const int j = blockIdx.x * 256 + t;
    const int jt = t >> 6;
    float ps = 0.f;
#pragma unroll 4
    for (int r = 0; r < 64; ++r) {
        const float gv = h2f(G[(i64)(r0 + r) * WH + j]);
        ps += gv * gv * fl[jt][r];
    }
    part[(i64)blockIdx.y * WH + j] = ps;
}

// -------- fused attention: P = [gs^2 * exp(m_half-o)/65536 * colS_j] @ axt^T, f16 partials.
// colS computed in-prologue from part. grid (2, 32, 16): z = chunk(0..7) + 8*batch-in-pair.
// (round-8 proven geometry)
template <int FULL>
__global__ __launch_bounds__(256) void k_attn(
    const unsigned short* __restrict__ G, const float* __restrict__ o,
    const float2* __restrict__ rowP, const float* __restrict__ part,
    const unsigned short* __restrict__ Bh, const unsigned short* __restrict__ Bl,
    unsigned short* __restrict__ Pw) {
    __shared__ __align__(16) short lL[4096];   // 8 KB: gs 128 rows x 32 k
    __shared__ __align__(16) short lBh[4096];  // 8 KB
    __shared__ __align__(16) short lBl[FULL ? 4096 : 8];
    __shared__ float lS[512];
    const int zb = blockIdx.z >> 3;            // batch within pair
    const int zc = blockIdx.z & 7;             // k-chunk
    G += (i64)zb * ((i64)WH * WH);
    o += (i64)zb * WH;
    rowP += (i64)zb * (64 * (i64)WH);
    part += (i64)zb * (64 * (i64)WH);
    Bh += (i64)zb * ((i64)WH * CD);
    if constexpr (FULL) Bl += (i64)zb * ((i64)WH * CD);
    Pw += (i64)zb * (8 * (i64)WH * CD);
    const int tid = threadIdx.x;
    const int w = tid >> 6, l = tid & 63;
    const int wm = w >> 1, wn = w & 1;
    const int bm = blockIdx.y * 128, bn = blockIdx.x * 128;
    const int l15 = l & 15, lq = l >> 4;
    const i64 koff = (i64)zc * 512;

    // colS for this k-chunk from part (same summation order as the old k_colreduce)
    {
        float C0 = 0.f, C1 = 0.f;
#pragma unroll 4
        for (int p = 0; p < 64; ++p) {
            C0 += part[(i64)p * WH + koff + tid];
            C1 += part[(i64)p * WH + koff + 256 + tid];
        }
        lS[tid] = 1.f / fmaxf(C0, 1e-12f);
        lS[tid + 256] = 1.f / fmaxf(C1, 1e-12f);
    }
    float o4[4];
#pragma unroll
    for (int i = 0; i < 4; ++i) o4[i] = o[bm + wm * 64 + i * 16 + l15];

    float fi[4];
    f32x4 acc[4][4] = {};
    for (int kt = 0; kt < 512; kt += 32) {
        __syncthreads();
#pragma unroll
        for (int rr = 0; rr < 2; ++rr) {
            const int r = w + rr * 4;          // region 0..7 (1 KB each) — gs staging
            const int kb = r >> 1, mh = r & 1;
            ld16_lds(G + (i64)(bm + mh * 64 + l) * WH + koff + kt + kb * 8,
                     (char*)lL + r * 1024);
        }
#pragma unroll
        for (int rr = 0; rr < 2; ++rr) {
            const int r = w + rr * 4;          // region 0..7
            const int kb = r >> 1, mh = r & 1;
            const i64 bo = (i64)(bn + mh * 64 + l) * WH + koff + kt + kb * 8;
            ld16_lds(Bh + bo, (char*)lBh + r * 1024);
            if constexpr (FULL) ld16_lds(Bl + bo, (char*)lBl + r * 1024);
        }
        // per-(row, 64-k-half) factor exp(m_half - o)/65536: refresh every other K-step
        if ((kt & 32) == 0) {
            const i64 half = (koff + kt) >> 6;
#pragma unroll
            for (int i = 0; i < 4; ++i)
                fi[i] = __expf(rowP[half * WH + bm + wm * 64 + i * 16 + l15].x - o4[i])
                      * (1.f / 65536.f);
        }
        __syncthreads();
        float sv[8];
        *(float4*)(sv)     = *(const float4*)(lS + kt + lq * 8);
        *(float4*)(sv + 4) = *(const float4*)(lS + kt + lq * 8 + 4);
        f16x8 bh[4], bl[4];
#pragma unroll
        for (int j = 0; j < 4; ++j) {
            const int ib = (lq * 128 + wn * 64 + j * 16 + l15) * 8;
            bh[j] = *(const f16x8*)(lBh + ib);
            if constexpr (FULL) bl[j] = *(const f16x8*)(lBl + ib);
        }
#pragma unroll
        for (int i = 0; i < 4; ++i) {
            const f16x8 graw = *(const f16x8*)(lL + (lq * 128 + wm * 64 + i * 16 + l15) * 8);
            const float fi_ = fi[i];
            f16x8 ah, al;
#pragma unroll
            for (int e = 0; e < 8; ++e) {
                const float gv = (float)graw[e];
                const float a = gv * gv * fi_ * sv[e];
                const _Float16 hh = (_Float16)a;
                ah[e] = hh;
                if constexpr (FULL) al[e] = (_Float16)(a - (float)hh);
            }
#pragma unroll
            for (int j = 0; j < 4; ++j) {
                acc[i][j] = __builtin_amdgcn_mfma_f32_16x16x32_f16(ah, bh[j], acc[i][j], 0, 0, 0);
                if constexpr (FULL) {
                    acc[i][j] = __builtin_amdgcn_mfma_f32_16x16x32_f16(ah, bl[j], acc[i][j], 0, 0, 0);
                    acc[i][j] = __builtin_amdgcn_mfma_f32_16x16x32_f16(al, bh[j], acc[i][j], 0, 0, 0);
                }
            }
        }
    }
    unsigned short* P = Pw + (i64)zc * ((i64)WH * CD);
#pragma unroll
    for (int i = 0; i < 4; ++i)
#pragma unroll
        for (int j = 0; j < 4; ++j) {
            const int n = bn + wn * 64 + j * 16 + l15;
            const int m0 = bm + wm * 64 + i * 16 + lq * 4;
#pragma unroll
            for (int r = 0; r < 4; ++r)
                P[(i64)(m0 + r) * CD + n] = f2h(acc[i][j][r]);
        }
}

// -------- reduce 8 f16 split-K partials into outf; grid (WHC/1024, 2=pair)
template <int SPLIT>
__global__ __launch_bounds__(256) void k_red(const unsigned short* __restrict__ Pw,
                                             float* __restrict__ outp,
                                             unsigned short* __restrict__ hi,
                                             unsigned short* __restrict__ lo) {
    const int b = blockIdx.y;
    Pw += (i64)b * (8 * (i64)WH * CD);
    outp += (i64)b * ((i64)WH * CD);
    if constexpr (SPLIT) {
        hi += (i64)b * ((i64)WH * CD);
        lo += (i64)b * ((i64)WH * CD);
    }
    const i64 i = ((i64)blockIdx.x * 256 + threadIdx.x) * 4;
    float4 a = *(const float4*)(outp + i);
#pragma unroll
    for (int z = 0; z < 8; ++z) {
        const ushort4 p = *(const ushort4*)(Pw + (i64)z * ((i64)WH * CD) + i);
        a.x += h2f(p.x); a.y += h2f(p.y); a.z += h2f(p.z); a.w += h2f(p.w);
    }
    *(float4*)(outp + i) = a;
    if constexpr (SPLIT) {
        ushort4 h, l2;
        h.x = f2h(a.x); l2.x = f2h(a.x - h2f(h.x));
        h.y = f2h(a.y); l2.y = f2h(a.y - h2f(h.y));
        h.z = f2h(a.z); l2.z = f2h(a.z - h2f(h.z));
        h.w = f2h(a.w); l2.w = f2h(a.w - h2f(h.w));
        *(ushort4*)(hi + i) = h;
        *(ushort4*)(lo + i) = l2;
    }
}

extern "C" void kernel_launch(void* const* d_in, const int* in_sizes, int n_in,
                              void* d_out, int out_size, void* d_ws, size_t ws_size,
                              hipStream_t stream) {
    (void)in_sizes; (void)n_in; (void)out_size; (void)ws_size;
    const float* skt = (const float*)d_in[0];
    const float* ref = (const float*)d_in[1];
    const float* Wa3 = (const float*)d_in[2];
    const float* ba3 = (const float*)d_in[3];
    const float* Wu3 = (const float*)d_in[4];
    const float* bu3 = (const float*)d_in[5];
    const float* Wa4 = (const float*)d_in[6];
    const float* ba4 = (const float*)d_in[7];
    const float* Wu4 = (const float*)d_in[8];
    const float* bu4 = (const float*)d_in[9];
    float* out = (float*)d_out;

    const i64 WHC = (i64)WH * CD;   // 1,048,576
    const i64 GM  = (i64)WH * WH;   // 16,777,216
    const i64 CC  = (i64)CD * CD;

    // workspace carve — ~175 MB (proven-safe: 204.5 MB ran previously)
    auto al = [](size_t x) { return (x + 255) & ~(size_t)255; };
    char* p = (char*)d_ws; size_t off = 0;
    auto carve = [&](size_t bytes) { void* r = p + off; off += al(bytes); return r; };
    unsigned short* Gb    = (unsigned short*)carve((size_t)2 * GM * 2);  // 67.1 MB  gs f16 x pair
    unsigned short* skthi = (unsigned short*)carve((size_t)4 * WHC * 2);
    unsigned short* sktlo = (unsigned short*)carve((size_t)4 * WHC * 2);
    unsigned short* refhi = (unsigned short*)carve((size_t)4 * WHC * 2);
    unsigned short* reflo = (unsigned short*)carve((size_t)4 * WHC * 2);
    unsigned short* ghi   = (unsigned short*)carve((size_t)4 * WHC * 2);
    unsigned short* glo   = (unsigned short*)carve((size_t)4 * WHC * 2); // 6x8.39 MB
    unsigned short* axthi = (unsigned short*)carve((size_t)4 * WHC * 2);
    unsigned short* axtlo = (unsigned short*)carve((size_t)4 * WHC * 2); // 16.8 MB
    float* ob             = (float*)carve((size_t)2 * WH * 4);
    float* partb          = (float*)carve((size_t)2 * 64 * WH * 4);      // 2.1 MB
    float2* rowPb         = (float2*)carve((size_t)2 * 64 * WH * 8);     // 4.2 MB
    unsigned short* Wthi  = (unsigned short*)carve((size_t)4 * CC * 2);
    unsigned short* Wtlo  = (unsigned short*)carve((size_t)4 * CC * 2);
    unsigned short* Pw    = (unsigned short*)carve((size_t)2 * 8 * WHC * 2); // 33.6 MB

    dim3 thr(256), ttr(32, 8);
    // batched transposes: one dispatch for skt+ref (8 z), one for the 4 weights
    {
        TransArgs ta{};
        for (int b = 0; b < 4; ++b) {
            ta.src[b] = skt + (i64)b * WHC;     ta.src[b + 4] = ref + (i64)b * WHC;
            ta.dhi[b] = skthi + (i64)b * WHC;   ta.dhi[b + 4] = refhi + (i64)b * WHC;
            ta.dlo[b] = sktlo + (i64)b * WHC;   ta.dlo[b + 4] = reflo + (i64)b * WHC;
        }
        k_transN<<<dim3(WH / 32, CD / 32, 8), ttr, 0, stream>>>(ta, CD, WH);
        TransArgs tw{};
        const float* ws[4] = { Wa3, Wu3, Wa4, Wu4 };
        for (int i = 0; i < 4; ++i) {
            tw.src[i] = ws[i];
            tw.dhi[i] = Wthi + (i64)i * CC;
            tw.dlo[i] = Wtlo + (i64)i * CC;
        }
        k_transN<<<dim3(CD / 32, CD / 32, 4), ttr, 0, stream>>>(tw, CD, CD);
    }

    // FULL3 = 1: stage A (split attn path, emits gen split); 0: stage B (hi-only attn)
    auto stage = [&](const unsigned short* shi, const unsigned short* slo,
                     const unsigned short* mhi, const unsigned short* mlo,
                     int widx, const float* ba, const float* bu, float* outf,
                     unsigned short* ohi, unsigned short* olo, int FULL3) {
        // merged: ax (4 batches) + r (4 batches) in one 512-block dispatch
        if (FULL3)
            k_gemm12<1><<<dim3(CD / 128, WH / 128, 8), thr, 0, stream>>>(
                shi, slo, mhi, mlo,
                Wthi + (i64)widx * CC, Wtlo + (i64)widx * CC,
                Wthi + (i64)(widx + 1) * CC, Wtlo + (i64)(widx + 1) * CC,
                ba, bu, axthi, axtlo, outf);
        else
            k_gemm12<0><<<dim3(CD / 128, WH / 128, 8), thr, 0, stream>>>(
                shi, slo, mhi, mlo,
                Wthi + (i64)widx * CC, nullptr,
                Wthi + (i64)(widx + 1) * CC, nullptr,
                ba, bu, axthi, axtlo, outf);
        for (int pb = 0; pb < 2; ++pb) {
            const i64 bo = (i64)(2 * pb) * WHC;
            // logits (pair) -> gs f16 (scaled sqrt-domain) + rowP
            k_logits<<<dim3(WH / 128, WH / 256, 2), thr, 0, stream>>>(
                shi + bo, slo + bo, mhi + bo, mlo + bo, Gb, rowPb, WHC);
            // o-finalize + column partials (pair)
            k_colpart<<<dim3(WH / 256, WH / 64, 2), thr, 0, stream>>>(Gb, rowPb, ob, partb);
            // attention (pair; colS in-prologue; split-K 8, f16 partial stores)
            if (FULL3)
                k_attn<1><<<dim3(CD / 128, WH / 128, 16), thr, 0, stream>>>(
                    Gb, ob, rowPb, partb, axthi + bo, axtlo + bo, Pw);
            else
                k_attn<0><<<dim3(CD / 128, WH / 128, 16), thr, 0, stream>>>(
                    Gb, ob, rowPb, partb, axthi + bo, nullptr, Pw);
            // outf += sum_z P[z]  (+ f16 split of gen for stage A)  (pair)
            if (ohi)
                k_red<1><<<dim3((unsigned)(WHC / 1024), 2), thr, 0, stream>>>(
                    Pw, outf + bo, ohi + bo, olo + bo);
            else
                k_red<0><<<dim3((unsigned)(WHC / 1024), 2), thr, 0, stream>>>(
                    Pw, outf + bo, nullptr, nullptr);
        }
    };

    // stage A: src = skt, msg = ref -> gen (accumulated in d_out, split to ghi/glo)
    stage(skthi, sktlo, refhi, reflo, 0, ba3, bu3, out, ghi, glo, 1);
    // stage B: src = msg = gen -> final output (overwrites d_out)
    stage(ghi, glo, ghi, glo, 2, ba4, bu4, out, nullptr, nullptr, 0);
}

// Round 12
// 909.285 us; speedup vs baseline: 1.3308x; 1.0270x over previous
//
#include <hip/hip_runtime.h>
#include <cstdint>
#include <cstddef>

#define WH 4096
#define CD 256
typedef long long i64;

typedef __attribute__((ext_vector_type(8))) _Float16 f16x8;
typedef __attribute__((ext_vector_type(4))) float f32x4;

#define AS1 __attribute__((address_space(1)))
#define AS3 __attribute__((address_space(3)))

__device__ __forceinline__ unsigned short f2h(float f) {
    _Float16 h = (_Float16)f;
    return __builtin_bit_cast(unsigned short, h);
}
__device__ __forceinline__ float h2f(unsigned short u) {
    return (float)__builtin_bit_cast(_Float16, u);
}
__device__ __forceinline__ void ld16_lds(const void* g, void* l) {
    __builtin_amdgcn_global_load_lds((AS1 void*)g, (AS3 void*)l, 16, 0, 0);
}

// -------- batched transpose f32 -> f16 split; per-z pre-offset pointers
struct TransArgs {
    const float* src[8];
    unsigned short* dhi[8];
    unsigned short* dlo[8];
};
__global__ __launch_bounds__(256) void k_transN(TransArgs ta, int RR, int CC) {
    __shared__ float t[32][33];
    const float* s = ta.src[blockIdx.z];
    unsigned short* dhi = ta.dhi[blockIdx.z];
    unsigned short* dlo = ta.dlo[blockIdx.z];
    const int c0 = blockIdx.x * 32, r0 = blockIdx.y * 32;
    const int tx = threadIdx.x, ty = threadIdx.y;
#pragma unroll
    for (int i = 0; i < 4; ++i)
        t[ty + i * 8][tx] = s[(i64)(r0 + ty + i * 8) * CC + c0 + tx];
    __syncthreads();
#pragma unroll
    for (int i = 0; i < 4; ++i) {
        const i64 idx = (i64)(c0 + ty + i * 8) * RR + r0 + tx;
        const float v = t[tx][ty + i * 8];
        const unsigned short hi = f2h(v);
        dhi[idx] = hi;
        dlo[idx] = f2h(v - h2f(hi));
    }
}

// -------- merged ax/r GEMM: grid (2, 32, 8). z<4: ax = relu(msg@Wa+ba) -> axt f16-split
// (transposed store). z>=4: r = relu(src@Wu+bu) + src -> outf f32. One dispatch = 512
// blocks = 2/CU. Residual read uses base pointers (single batch offset in idx — r11 fix).
template <int SPLIT3>
__global__ __launch_bounds__(256) void k_gemm12(
    const unsigned short* __restrict__ Shi, const unsigned short* __restrict__ Slo,
    const unsigned short* __restrict__ Mhi, const unsigned short* __restrict__ Mlo,
    const unsigned short* __restrict__ WAh, const unsigned short* __restrict__ WAl,
    const unsigned short* __restrict__ WUh, const unsigned short* __restrict__ WUl,
    const float* __restrict__ ba, const float* __restrict__ bu,
    unsigned short* __restrict__ axh, unsigned short* __restrict__ axl,
    float* __restrict__ outf) {
    __shared__ __align__(16) short lA[SPLIT3 ? 8192 : 4096];
    __shared__ __align__(16) short lB[SPLIT3 ? 8192 : 4096];
    const int mode = blockIdx.z >> 2;          // 0: ax, 1: r
    const int zb = blockIdx.z & 3;             // batch
    const i64 WHC = (i64)WH * CD;
    const unsigned short* A  = (mode ? Shi : Mhi) + (i64)zb * WHC;
    const unsigned short* A2 = SPLIT3 ? ((mode ? Slo : Mlo) + (i64)zb * WHC) : nullptr;
    const unsigned short* B  = mode ? WUh : WAh;
    const unsigned short* B2 = SPLIT3 ? (mode ? WUl : WAl) : nullptr;
    const float* bias = mode ? bu : ba;

    const int tid = threadIdx.x;
    const int w = tid >> 6, l = tid & 63;
    const int wm = w >> 1, wn = w & 1;
    const int bm = blockIdx.y * 128, bn = blockIdx.x * 128;
    const int l15 = l & 15, lq = l >> 4;

    f32x4 acc[4][4] = {};

    for (int kt = 0; kt < CD; kt += 32) {
        __syncthreads();
#pragma unroll
        for (int rr = 0; rr < 2; ++rr) {
            const int r = w + rr * 4;          // region 0..7
            const int kb = r >> 1, mh = r & 1;
            const int row = mh * 64 + l;
            const i64 ao = (i64)(bm + row) * CD + kt + kb * 8;
            const i64 bo = (i64)(bn + row) * CD + kt + kb * 8;
            ld16_lds(A + ao, (char*)lA + r * 1024);
            ld16_lds(B + bo, (char*)lB + r * 1024);
            if constexpr (SPLIT3) {
                ld16_lds(A2 + ao, (char*)lA + 8192 + r * 1024);
                ld16_lds(B2 + bo, (char*)lB + 8192 + r * 1024);
            }
        }
        __syncthreads();
        f16x8 ah[4], bh[4], al[4], bl[4];
#pragma unroll
        for (int i = 0; i < 4; ++i) {
            const int ia = (lq * 128 + wm * 64 + i * 16 + l15) * 8;
            const int ib = (lq * 128 + wn * 64 + i * 16 + l15) * 8;
            ah[i] = *(const f16x8*)(lA + ia);
            bh[i] = *(const f16x8*)(lB + ib);
            if constexpr (SPLIT3) {
                al[i] = *(const f16x8*)(lA + 4096 + ia);
                bl[i] = *(const f16x8*)(lB + 4096 + ib);
            }
        }
#pragma unroll
        for (int i = 0; i < 4; ++i)
#pragma unroll
            for (int j = 0; j < 4; ++j) {
                acc[i][j] = __builtin_amdgcn_mfma_f32_16x16x32_f16(ah[i], bh[j], acc[i][j], 0, 0, 0);
                if constexpr (SPLIT3) {
                    acc[i][j] = __builtin_amdgcn_mfma_f32_16x16x32_f16(ah[i], bl[j], acc[i][j], 0, 0, 0);
                    acc[i][j] = __builtin_amdgcn_mfma_f32_16x16x32_f16(al[i], bh[j], acc[i][j], 0, 0, 0);
                }
            }
    }

#pragma unroll
    for (int i = 0; i < 4; ++i)
#pragma unroll
        for (int j = 0; j < 4; ++j) {
            const int n = bn + wn * 64 + j * 16 + l15;
            const int m0 = bm + wm * 64 + i * 16 + lq * 4;
            const float bv = bias[n];
            if (mode == 0) {                   // ax -> transposed f16-split
                unsigned short hv[4], lv[4];
#pragma unroll
                for (int r = 0; r < 4; ++r) {
                    const float v = fmaxf(acc[i][j][r] + bv, 0.f);
                    hv[r] = f2h(v);
                    lv[r] = f2h(v - h2f(hv[r]));
                }
                const i64 tb = (i64)zb * WHC + (i64)n * WH + m0;
                *(ushort4*)(axh + tb) = make_ushort4(hv[0], hv[1], hv[2], hv[3]);
                *(ushort4*)(axl + tb) = make_ushort4(lv[0], lv[1], lv[2], lv[3]);
            } else {                           // r -> f32 + split residual
#pragma unroll
                for (int r = 0; r < 4; ++r) {
                    const i64 idx = (i64)zb * WHC + (i64)(m0 + r) * CD + n;
                    float v = fmaxf(acc[i][j][r] + bv, 0.f);
                    v += h2f(Shi[idx]) + h2f(Slo[idx]);   // single batch offset (in idx)
                    outf[idx] = v;
                }
            }
        }
}

// -------- logits GEMM (split-3), 256x128 tile, BATCH-PAIR z -> gs = 256*exp((L-m_half)/2)
// f16, plus rowP. z = blockIdx.z selects batch within the pair (decorrelated co-residency).
// rowP layout: [64 half-tiles][WH rows] of (m_half, expsum_half); half = blockIdx.x*2 + wn.
__global__ __launch_bounds__(256, 2) void k_logits(
    const unsigned short* __restrict__ A, const unsigned short* __restrict__ A2,
    const unsigned short* __restrict__ B, const unsigned short* __restrict__ B2,
    unsigned short* __restrict__ G, float2* __restrict__ rowP, i64 sAB) {
    __shared__ __align__(16) short lA[16384];  // 32 KB: A-hi @0, A-lo @+8192 shorts
    __shared__ __align__(16) short lB[8192];   // 16 KB: B-hi @0, B-lo @+4096 shorts
    const int z = blockIdx.z;
    A += (i64)z * sAB; A2 += (i64)z * sAB;
    B += (i64)z * sAB; B2 += (i64)z * sAB;
    G += (i64)z * ((i64)WH * WH);
    rowP += (i64)z * (64 * (i64)WH);
    const int tid = threadIdx.x;
    const int w = tid >> 6, l = tid & 63;
    const int wm = w >> 1, wn = w & 1;
    const int bm = blockIdx.y * 256, bn = blockIdx.x * 128;
    const int l15 = l & 15, lq = l >> 4;

    f32x4 acc[8][4] = {};

    for (int kt = 0; kt < CD; kt += 32) {
        __syncthreads();
#pragma unroll
        for (int rr = 0; rr < 12; ++rr) {
            const int r = w + rr * 4;          // 0..47 (wave-uniform branch below)
            if (r < 32) {                       // A: 16 hi + 16 lo regions (256 rows)
                const int ra = r & 15;
                const int kb = ra >> 2, nh = ra & 3;
                const i64 ao = (i64)(bm + nh * 64 + l) * CD + kt + kb * 8;
                if (r < 16) ld16_lds(A + ao, (char*)lA + ra * 1024);
                else        ld16_lds(A2 + ao, (char*)lA + 16384 + ra * 1024);
            } else {                            // B: 8 hi + 8 lo regions (128 rows)
                const int rb = r & 7;
                const int kb = rb >> 1, mh = rb & 1;
                const i64 bo = (i64)(bn + mh * 64 + l) * CD + kt + kb * 8;
                if (r < 40) ld16_lds(B + bo, (char*)lB + rb * 1024);
                else        ld16_lds(B2 + bo, (char*)lB + 8192 + rb * 1024);
            }
        }
        __syncthreads();
        f16x8 bh[4], bl[4];
#pragma unroll
        for (int j = 0; j < 4; ++j) {
            const int ib = (lq * 128 + wn * 64 + j * 16 + l15) * 8;
            bh[j] = *(const f16x8*)(lB + ib);
            bl[j] = *(const f16x8*)(lB + 4096 + ib);
        }
#pragma unroll
        for (int i = 0; i < 8; ++i) {
            const int ia = (lq * 256 + wm * 128 + i * 16 + l15) * 8;
            const f16x8 ah = *(const f16x8*)(lA + ia);
            const f16x8 al = *(const f16x8*)(lA + 8192 + ia);
#pragma unroll
            for (int j = 0; j < 4; ++j) {
                acc[i][j] = __builtin_amdgcn_mfma_f32_16x16x32_f16(ah, bh[j], acc[i][j], 0, 0, 0);
                acc[i][j] = __builtin_amdgcn_mfma_f32_16x16x32_f16(ah, bl[j], acc[i][j], 0, 0, 0);
                acc[i][j] = __builtin_amdgcn_mfma_f32_16x16x32_f16(al, bh[j], acc[i][j], 0, 0, 0);
            }
        }
    }

    // epilogue: per (row, wn-half): m over 64 cols, gs f16 store, exact f32 expsum, rowP store
#pragma unroll
    for (int i = 0; i < 8; ++i)
#pragma unroll
        for (int r = 0; r < 4; ++r) {
            const int grow = bm + wm * 128 + i * 16 + lq * 4 + r;
            float m = fmaxf(fmaxf(acc[i][0][r], acc[i][1][r]), fmaxf(acc[i][2][r], acc[i][3][r]));
            m = fmaxf(m, __shfl_xor(m, 1));
            m = fmaxf(m, __shfl_xor(m, 2));
            m = fmaxf(m, __shfl_xor(m, 4));
            m = fmaxf(m, __shfl_xor(m, 8));
            float s = 0.f;
#pragma unroll
            for (int j = 0; j < 4; ++j) {
                const float es = __expf((acc[i][j][r] - m) * 0.5f);
                s += es * es;   // exact exp(L-m) rowsum in f32
                G[(i64)grow * WH + bn + wn * 64 + j * 16 + l15] = f2h(es * 256.f);
            }
            s += __shfl_xor(s, 1); s += __shfl_xor(s, 2);
            s += __shfl_xor(s, 4); s += __shfl_xor(s, 8);
            if (l15 == 0)
                rowP[(i64)(blockIdx.x * 2 + wn) * WH + grow] = make_float2(m, s);
        }
}

// -------- fused: merge rowP (64 halves) -> o; col partials = sum gs^2 * factor.
// factor = exp(m_half - o)/65536 undoes the sqrt-domain scaling. grid (16, 64, 2=pair).
__global__ __launch_bounds__(256) void k_colpart(const unsigned short* __restrict__ G,
                                                 const float2* __restrict__ rowP,
                                                 float* __restrict__ o,
                                                 float* __restrict__ part) {
    __shared__ float os[64];
    __shared__ float fl[4][64];
    const int z = blockIdx.z;
    G += (i64)z * ((i64)WH * WH);
    rowP += (i64)z * (64 * (i64)WH);
    o += (i64)z * WH;
    part += (i64)z * (64 * (i64)WH);
    const int t = threadIdx.x;
    const int r0 = blockIdx.y * 64;
    if (t < 64) {
        float M = -3.4e38f, S = 0.f;
        for (int x = 0; x < 64; ++x) {
            const float2 p = rowP[(i64)x * WH + r0 + t];
            const float nm = fmaxf(M, p.x);
            S = S * __expf(M - nm) + p.y * __expf(p.x - nm);
            M = nm;
        }
        const float ov = M + __logf(S);
        os[t] = ov;
        if (blockIdx.x == 0) o[r0 + t] = ov;
    }
    __syncthreads();
    {   // 256 factors: (r, jt) for this block's 4 column half-tiles
        const int jt = t & 3, r = t >> 2;
        fl[jt][r] = __expf(rowP[(i64)(blockIdx.x * 4 + jt) * WH + r0 + r].x - os[r])
                  * (1.f / 65536.f);
    }
    __syncthreads();
    const int j = blockIdx.x * 256 + t;
    const int jt = t >> 6;
    float ps = 0.f;
#pragma unroll 4
    for (int r = 0; r < 64; ++r) {
        const float gv = h2f(G[(i64)(r0 + r) * WH + j]);
        ps += gv * gv * fl[jt][r];
    }
    part[(i64)blockIdx.y * WH + j] = ps;
}

// -------- fused attention: P = [gs^2 * exp(m_half-o)/65536 * colS_j] @ axt^T, f16 partials.
// 128x256 output tiles (full CD width): each wave's A-fragment (expensive VALU construction)
// feeds 8 j-MFMAs instead of 4; G row-panels read once per (bm, chunk).
// grid (32, 16): x = row tile, y = zc(0..7) + 8*batch-in-pair.  [r9 code, exonerated by
// r9/r10 differential: identical absmax with/without this change -> bug was in gemm12]
template <int FULL>
__global__ __launch_bounds__(256, 2) void k_attn(
    const unsigned short* __restrict__ G, const float* __restrict__ o,
    const float2* __restrict__ rowP, const float* __restrict__ part,
    const unsigned short* __restrict__ Bh, const unsigned short* __restrict__ Bl,
    unsigned short* __restrict__ Pw) {
    __shared__ __align__(16) short lL[4096];   // 8 KB: gs 128 rows x 32 k
    __shared__ __align__(16) short lBh[8192];  // 16 KB: 256 cols x 32 k
    __shared__ __align__(16) short lBl[FULL ? 8192 : 8];
    __shared__ float lS[512];
    const int zb = blockIdx.y >> 3;            // batch within pair
    const int zc = blockIdx.y & 7;             // k-chunk
    G += (i64)zb * ((i64)WH * WH);
    o += (i64)zb * WH;
    rowP += (i64)zb * (64 * (i64)WH);
    part += (i64)zb * (64 * (i64)WH);
    Bh += (i64)zb * ((i64)WH * CD);
    if constexpr (FULL) Bl += (i64)zb * ((i64)WH * CD);
    Pw += (i64)zb * (8 * (i64)WH * CD);
    const int tid = threadIdx.x;
    const int w = tid >> 6, l = tid & 63;
    const int wm = w >> 1, wn = w & 1;         // wm: 64-row half, wn: 128-col half
    const int bm = blockIdx.x * 128;
    const int l15 = l & 15, lq = l >> 4;
    const i64 koff = (i64)zc * 512;

    // colS for this k-chunk from part (same summation order as the old k_colreduce)
    {
        float C0 = 0.f, C1 = 0.f;
#pragma unroll 4
        for (int p = 0; p < 64; ++p) {
            C0 += part[(i64)p * WH + koff + tid];
            C1 += part[(i64)p * WH + koff + 256 + tid];
        }
        lS[tid] = 1.f / fmaxf(C0, 1e-12f);
        lS[tid + 256] = 1.f / fmaxf(C1, 1e-12f);
    }
    float o4[4];
#pragma unroll
    for (int i = 0; i < 4; ++i) o4[i] = o[bm + wm * 64 + i * 16 + l15];

    float fi[4];
    f32x4 acc[4][8] = {};
    for (int kt = 0; kt < 512; kt += 32) {
        __syncthreads();
#pragma unroll
        for (int rr = 0; rr < 2; ++rr) {
            const int r = w + rr * 4;          // G region 0..7 (1 KB each)
            const int kb = r >> 1, mh = r & 1;
            ld16_lds(G + (i64)(bm + mh * 64 + l) * WH + koff + kt + kb * 8,
                     (char*)lL + r * 1024);
        }
#pragma unroll
        for (int rr = 0; rr < 4; ++rr) {
            const int r = w + rr * 4;          // B region 0..15: kb = r>>2, col-quarter = r&3
            const int kb = r >> 2, rh = r & 3;
            const i64 bo = (i64)(rh * 64 + l) * WH + koff + kt + kb * 8;
            ld16_lds(Bh + bo, (char*)lBh + r * 1024);
            if constexpr (FULL) ld16_lds(Bl + bo, (char*)lBl + r * 1024);
        }
        // per-(row, 64-k-half) factor exp(m_half - o)/65536: refresh every other K-step
        if ((kt & 32) == 0) {
            const i64 half = (koff + kt) >> 6;
#pragma unroll
            for (int i = 0; i < 4; ++i)
                fi[i] = __expf(rowP[half * WH + bm + wm * 64 + i * 16 + l15].x - o4[i])
                      * (1.f / 65536.f);
        }
        __syncthreads();
        float sv[8];
        *(float4*)(sv)     = *(const float4*)(lS + kt + lq * 8);
        *(float4*)(sv + 4) = *(const float4*)(lS + kt + lq * 8 + 4);
#pragma unroll
        for (int i = 0; i < 4; ++i) {
            const f16x8 graw = *(const f16x8*)(lL + (lq * 128 + wm * 64 + i * 16 + l15) * 8);
            const float fi_ = fi[i];
            f16x8 ah, al;
#pragma unroll
            for (int e = 0; e < 8; ++e) {
                const float gv = (float)graw[e];
                const float a = gv * gv * fi_ * sv[e];
                const _Float16 hh = (_Float16)a;
                ah[e] = hh;
                if constexpr (FULL) al[e] = (_Float16)(a - (float)hh);
            }
#pragma unroll
            for (int j = 0; j < 8; ++j) {
                const int ib = (lq * 256 + wn * 128 + j * 16 + l15) * 8;
                const f16x8 bh = *(const f16x8*)(lBh + ib);
                acc[i][j] = __builtin_amdgcn_mfma_f32_16x16x32_f16(ah, bh, acc[i][j], 0, 0, 0);
                if constexpr (FULL) {
                    const f16x8 bl = *(const f16x8*)(lBl + ib);
                    acc[i][j] = __builtin_amdgcn_mfma_f32_16x16x32_f16(ah, bl, acc[i][j], 0, 0, 0);
                    acc[i][j] = __builtin_amdgcn_mfma_f32_16x16x32_f16(al, bh, acc[i][j], 0, 0, 0);
                }
            }
        }
    }
    unsigned short* P = Pw + (i64)zc * ((i64)WH * CD);
#pragma unroll
    for (int i = 0; i < 4; ++i)
#pragma unroll
        for (int j = 0; j < 8; ++j) {
            const int n = wn * 128 + j * 16 + l15;
            const int m0 = bm + wm * 64 + i * 16 + lq * 4;
#pragma unroll
            for (int r = 0; r < 4; ++r)
                P[(i64)(m0 + r) * CD + n] = f2h(acc[i][j][r]);
        }
}

// -------- reduce 8 f16 split-K partials into outf; grid (WHC/1024, 2=pair)
template <int SPLIT>
__global__ __launch_bounds__(256) void k_red(const unsigned short* __restrict__ Pw,
                                             float* __restrict__ outp,
                                             unsigned short* __restrict__ hi,
                                             unsigned short* __restrict__ lo) {
    const int b = blockIdx.y;
    Pw += (i64)b * (8 * (i64)WH * CD);
    outp += (i64)b * ((i64)WH * CD);
    if constexpr (SPLIT) {
        hi += (i64)b * ((i64)WH * CD);
        lo += (i64)b * ((i64)WH * CD);
    }
    const i64 i = ((i64)blockIdx.x * 256 + threadIdx.x) * 4;
    float4 a = *(const float4*)(outp + i);
#pragma unroll
    for (int z = 0; z < 8; ++z) {
        const ushort4 p = *(const ushort4*)(Pw + (i64)z * ((i64)WH * CD) + i);
        a.x += h2f(p.x); a.y += h2f(p.y); a.z += h2f(p.z); a.w += h2f(p.w);
    }
    *(float4*)(outp + i) = a;
    if constexpr (SPLIT) {
        ushort4 h, l2;
        h.x = f2h(a.x); l2.x = f2h(a.x - h2f(h.x));
        h.y = f2h(a.y); l2.y = f2h(a.y - h2f(h.y));
        h.z = f2h(a.z); l2.z = f2h(a.z - h2f(h.z));
        h.w = f2h(a.w); l2.w = f2h(a.w - h2f(h.w));
        *(ushort4*)(hi + i) = h;
        *(ushort4*)(lo + i) = l2;
    }
}

extern "C" void kernel_launch(void* const* d_in, const int* in_sizes, int n_in,
                              void* d_out, int out_size, void* d_ws, size_t ws_size,
                              hipStream_t stream) {
    (void)in_sizes; (void)n_in; (void)out_size; (void)ws_size;
    const float* skt = (const float*)d_in[0];
    const float* ref = (const float*)d_in[1];
    const float* Wa3 = (const float*)d_in[2];
    const float* ba3 = (const float*)d_in[3];
    const float* Wu3 = (const float*)d_in[4];
    const float* bu3 = (const float*)d_in[5];
    const float* Wa4 = (const float*)d_in[6];
    const float* ba4 = (const float*)d_in[7];
    const float* Wu4 = (const float*)d_in[8];
    const float* bu4 = (const float*)d_in[9];
    float* out = (float*)d_out;

    const i64 WHC = (i64)WH * CD;   // 1,048,576
    const i64 GM  = (i64)WH * WH;   // 16,777,216
    const i64 CC  = (i64)CD * CD;

    // workspace carve — ~175 MB (proven-safe: 204.5 MB ran previously)
    auto al = [](size_t x) { return (x + 255) & ~(size_t)255; };
    char* p = (char*)d_ws; size_t off = 0;
    auto carve = [&](size_t bytes) { void* r = p + off; off += al(bytes); return r; };
    unsigned short* Gb    = (unsigned short*)carve((size_t)2 * GM * 2);  // 67.1 MB  gs f16 x pair
    unsigned short* skthi = (unsigned short*)carve((size_t)4 * WHC * 2);
    unsigned short* sktlo = (unsigned short*)carve((size_t)4 * WHC * 2);
    unsigned short* refhi = (unsigned short*)carve((size_t)4 * WHC * 2);
    unsigned short* reflo = (unsigned short*)carve((size_t)4 * WHC * 2);
    unsigned short* ghi   = (unsigned short*)carve((size_t)4 * WHC * 2);
    unsigned short* glo   = (unsigned short*)carve((size_t)4 * WHC * 2); // 6x8.39 MB
    unsigned short* axthi = (unsigned short*)carve((size_t)4 * WHC * 2);
    unsigned short* axtlo = (unsigned short*)carve((size_t)4 * WHC * 2); // 16.8 MB
    float* ob             = (float*)carve((size_t)2 * WH * 4);
    float* partb          = (float*)carve((size_t)2 * 64 * WH * 4);      // 2.1 MB
    float2* rowPb         = (float2*)carve((size_t)2 * 64 * WH * 8);     // 4.2 MB
    unsigned short* Wthi  = (unsigned short*)carve((size_t)4 * CC * 2);
    unsigned short* Wtlo  = (unsigned short*)carve((size_t)4 * CC * 2);
    unsigned short* Pw    = (unsigned short*)carve((size_t)2 * 8 * WHC * 2); // 33.6 MB

    dim3 thr(256), ttr(32, 8);
    // batched transposes: one dispatch for skt+ref (8 z), one for the 4 weights
    {
        TransArgs ta{};
        for (int b = 0; b < 4; ++b) {
            ta.src[b] = skt + (i64)b * WHC;     ta.src[b + 4] = ref + (i64)b * WHC;
            ta.dhi[b] = skthi + (i64)b * WHC;   ta.dhi[b + 4] = refhi + (i64)b * WHC;
            ta.dlo[b] = sktlo + (i64)b * WHC;   ta.dlo[b + 4] = reflo + (i64)b * WHC;
        }
        k_transN<<<dim3(WH / 32, CD / 32, 8), ttr, 0, stream>>>(ta, CD, WH);
        TransArgs tw{};
        const float* ws[4] = { Wa3, Wu3, Wa4, Wu4 };
        for (int i = 0; i < 4; ++i) {
            tw.src[i] = ws[i];
            tw.dhi[i] = Wthi + (i64)i * CC;
            tw.dlo[i] = Wtlo + (i64)i * CC;
        }
        k_transN<<<dim3(CD / 32, CD / 32, 4), ttr, 0, stream>>>(tw, CD, CD);
    }

    // FULL3 = 1: stage A (split attn path, emits gen split); 0: stage B (hi-only attn)
    auto stage = [&](const unsigned short* shi, const unsigned short* slo,
                     const unsigned short* mhi, const unsigned short* mlo,
                     int widx, const float* ba, const float* bu, float* outf,
                     unsigned short* ohi, unsigned short* olo, int FULL3) {
        // merged: ax (4 batches) + r (4 batches) in one 512-block dispatch
        if (FULL3)
            k_gemm12<1><<<dim3(CD / 128, WH / 128, 8), thr, 0, stream>>>(
                shi, slo, mhi, mlo,
                Wthi + (i64)widx * CC, Wtlo + (i64)widx * CC,
                Wthi + (i64)(widx + 1) * CC, Wtlo + (i64)(widx + 1) * CC,
                ba, bu, axthi, axtlo, outf);
        else
            k_gemm12<0><<<dim3(CD / 128, WH / 128, 8), thr, 0, stream>>>(
                shi, slo, mhi, mlo,
                Wthi + (i64)widx * CC, nullptr,
                Wthi + (i64)(widx + 1) * CC, nullptr,
                ba, bu, axthi, axtlo, outf);
        for (int pb = 0; pb < 2; ++pb) {
            const i64 bo = (i64)(2 * pb) * WHC;
            // logits (pair) -> gs f16 (scaled sqrt-domain) + rowP
            k_logits<<<dim3(WH / 128, WH / 256, 2), thr, 0, stream>>>(
                shi + bo, slo + bo, mhi + bo, mlo + bo, Gb, rowPb, WHC);
            // o-finalize + column partials (pair)
            k_colpart<<<dim3(WH / 256, WH / 64, 2), thr, 0, stream>>>(Gb, rowPb, ob, partb);
            // attention (pair; 128x256 tiles; colS in-prologue; split-K 8, f16 partials)
            if (FULL3)
                k_attn<1><<<dim3(WH / 128, 16), thr, 0, stream>>>(
                    Gb, ob, rowPb, partb, axthi + bo, axtlo + bo, Pw);
            else
                k_attn<0><<<dim3(WH / 128, 16), thr, 0, stream>>>(
                    Gb, ob, rowPb, partb, axthi + bo, nullptr, Pw);
            // outf += sum_z P[z]  (+ f16 split of gen for stage A)  (pair)
            if (ohi)
                k_red<1><<<dim3((unsigned)(WHC / 1024), 2), thr, 0, stream>>>(
                    Pw, outf + bo, ohi + bo, olo + bo);
            else
                k_red<0><<<dim3((unsigned)(WHC / 1024), 2), thr, 0, stream>>>(
                    Pw, outf + bo, nullptr, nullptr);
        }
    };

    // stage A: src = skt, msg = ref -> gen (accumulated in d_out, split to ghi/glo)
    stage(skthi, sktlo, refhi, reflo, 0, ba3, bu3, out, ghi, glo, 1);
    // stage B: src = msg = gen -> final output (overwrites d_out)
    stage(ghi, glo, ghi, glo, 2, ba4, bu4, out, nullptr, nullptr, 0);
}